// Round 2
// baseline (782.925 us; speedup 1.0000x reference)
//
#include <hip/hip_runtime.h>

#define IN_C  128
#define HID_C 128
#define OUT_CC 64

// ---------------- edge-index dtype probe ----------------
// If edge_index arrived as raw int64 (little-endian, values < 50000), the
// int32 view looks like (v,0,v,0,...). Detect: odd slots all zero, some even
// slot nonzero. Writes stride (1=int32, 2=int64-low-halves) into *flag.
__global__ void k_detect(const int* __restrict__ ei, int* __restrict__ flag) {
    if (blockIdx.x == 0 && threadIdx.x == 0) {
        int odd_zero = 1, any_even = 0;
        for (int i = 0; i < 64; ++i) {
            if (ei[2 * i + 1] != 0) odd_zero = 0;
            if (ei[2 * i] != 0) any_even = 1;
        }
        *flag = (odd_zero && any_even) ? 2 : 1;
    }
}

// ---------------- degree / norm ----------------
__global__ void k_deg(const int* __restrict__ ei, const int* __restrict__ flag,
                      float* __restrict__ deg, int E) {
    int i = blockIdx.x * blockDim.x + threadIdx.x;
    if (i >= E) return;
    int stride = *flag;
    int d = ei[(size_t)stride * ((size_t)E + i)];   // dst row, element i
    atomicAdd(&deg[d], 1.0f);
}

__global__ void k_dinv(float* __restrict__ deg, int N) {
    int i = blockIdx.x * blockDim.x + threadIdx.x;
    if (i < N) deg[i] = rsqrtf(deg[i] + 1.0f);      // +1 = self-loop
}

// ---------------- GEMM1: h[N,128] = x[N,128] @ W1[128,128] (f32) ----------------
__global__ __launch_bounds__(128) void k_gemm1(const float* __restrict__ x,
                                               const float* __restrict__ W,
                                               float* __restrict__ h, int N) {
    __shared__ float xs[4][IN_C];
    const int row0 = blockIdx.x * 4;
    const int c = threadIdx.x;                       // one output column per thread
    #pragma unroll
    for (int r = 0; r < 4; ++r) {
        int rr = row0 + r;
        xs[r][c] = (rr < N) ? x[(size_t)rr * IN_C + c] : 0.0f;
    }
    __syncthreads();
    float acc[4] = {0.f, 0.f, 0.f, 0.f};
    for (int k = 0; k < IN_C; ++k) {
        float w = W[k * HID_C + c];
        #pragma unroll
        for (int r = 0; r < 4; ++r) acc[r] += xs[r][k] * w;
    }
    #pragma unroll
    for (int r = 0; r < 4; ++r) {
        int rr = row0 + r;
        if (rr < N) h[(size_t)rr * HID_C + c] = acc[r];
    }
}

// ---------------- GEMM2: h2[N,64] = relu(agg1[N,128] + b1) @ W2[128,64] ----------------
__global__ __launch_bounds__(256) void k_gemm2(const float* __restrict__ agg1,
                                               const float* __restrict__ b1,
                                               const float* __restrict__ W2,
                                               float* __restrict__ h2, int N) {
    __shared__ float hs[4][HID_C];
    const int row0 = blockIdx.x * 4;
    const int tid = threadIdx.x;
    for (int i = tid; i < 4 * HID_C; i += 256) {
        int r = i >> 7, k = i & 127;
        int rr = row0 + r;
        float v = (rr < N) ? agg1[(size_t)rr * HID_C + k] + b1[k] : 0.0f;
        hs[r][k] = fmaxf(v, 0.0f);                   // fused bias + ReLU
    }
    __syncthreads();
    const int r = tid >> 6;
    const int c = tid & 63;
    float acc = 0.0f;
    for (int k = 0; k < HID_C; ++k)
        acc += hs[r][k] * W2[k * OUT_CC + c];
    int rr = row0 + r;
    if (rr < N) h2[(size_t)rr * OUT_CC + c] = acc;
}

// ---------------- aggregation: out[dst] += feat[src]*dinv[s]*dinv[d], + self-loops ----
template <int C>
__global__ __launch_bounds__(256) void k_agg(const float* __restrict__ feat,
                                             const int* __restrict__ ei,
                                             const int* __restrict__ flag,
                                             const float* __restrict__ dinv,
                                             float* __restrict__ out,
                                             int E, int N) {
    const int ipb = 256 / C;
    long long item = (long long)blockIdx.x * ipb + threadIdx.x / C;
    const int c = threadIdx.x % C;
    if (item >= (long long)E + N) return;
    int s, d;
    if (item < E) {
        int stride = *flag;
        s = ei[(size_t)stride * item];
        d = ei[(size_t)stride * ((size_t)E + item)];
    } else {
        s = d = (int)(item - E);
    }
    float w = dinv[s] * dinv[d];
    atomicAdd(&out[(size_t)d * C + c], feat[(size_t)s * C + c] * w);
}

// ---------------- epilogue: out = agg2 + b2 (f32) ----------------
__global__ void k_final(const float* __restrict__ agg2, const float* __restrict__ b2,
                        float* __restrict__ out, int M) {
    int i = blockIdx.x * blockDim.x + threadIdx.x;
    if (i < M) out[i] = agg2[i] + b2[i & (OUT_CC - 1)];
}

extern "C" void kernel_launch(void* const* d_in, const int* in_sizes, int n_in,
                              void* d_out, int out_size, void* d_ws, size_t ws_size,
                              hipStream_t stream) {
    const float* x  = (const float*)d_in[0];
    const int*   ei = (const int*)d_in[1];
    const float* W1 = (const float*)d_in[2];
    const float* b1 = (const float*)d_in[3];
    const float* W2 = (const float*)d_in[4];
    const float* b2 = (const float*)d_in[5];

    const int N = in_sizes[0] / IN_C;               // 50000
    const int E = in_sizes[1] / 2;                  // 800000

    char* ws = (char*)d_ws;
    int*   flag = (int*)ws;                         // [0,64)
    float* dinv = (float*)(ws + 64);                // N f32 -> [64, 200064)
    float* h    = (float*)(ws + 204800);            // N*128 f32 (reused as h2: N*64)
    float* agg  = (float*)(ws + 204800 + (size_t)N * HID_C * 4); // N*128 f32 (reused as agg2)

    hipMemsetAsync(dinv, 0, (size_t)N * 4, stream);
    hipMemsetAsync(agg, 0, (size_t)N * HID_C * 4, stream);

    k_detect<<<1, 64, 0, stream>>>(ei, flag);
    k_deg<<<(E + 255) / 256, 256, 0, stream>>>(ei, flag, dinv, E);
    k_dinv<<<(N + 255) / 256, 256, 0, stream>>>(dinv, N);

    // layer 1
    k_gemm1<<<(N + 3) / 4, 128, 0, stream>>>(x, W1, h, N);
    {
        const int ipb = 256 / HID_C;                // 2 items per block
        long long items = (long long)E + N;
        int blocks = (int)((items + ipb - 1) / ipb);
        k_agg<HID_C><<<blocks, 256, 0, stream>>>(h, ei, flag, dinv, agg, E, N);
    }

    // layer 2 (h region reused for h2; agg region re-zeroed for agg2)
    float* h2   = h;
    float* agg2 = agg;
    k_gemm2<<<(N + 3) / 4, 256, 0, stream>>>(agg, b1, W2, h2, N);
    hipMemsetAsync(agg2, 0, (size_t)N * OUT_CC * 4, stream);
    {
        const int ipb = 256 / OUT_CC;               // 4 items per block
        long long items = (long long)E + N;
        int blocks = (int)((items + ipb - 1) / ipb);
        k_agg<OUT_CC><<<blocks, 256, 0, stream>>>(h2, ei, flag, dinv, agg2, E, N);
    }

    k_final<<<((size_t)N * OUT_CC + 255) / 256, 256, 0, stream>>>(agg2, b2, (float*)d_out, N * OUT_CC);
}

// Round 3
// 438.660 us; speedup vs baseline: 1.7848x; 1.7848x over previous
//
#include <hip/hip_runtime.h>

#define IN_C  128
#define HID_C 128
#define OUT_CC 64

// ---- ws layout (bytes) ----
// deg/fill  int[N]      @ 0
// row_ptr   int[N+1]    @ 204800
// dinv      float[N]    @ 409600
// col       int[E]      @ 614400
// h         float[N*128]@ 4000000    (reused as h2: float[N*64] after agg1)
// agg1      float[N*128]@ 29600000
// flag      int         @ 55200000
// total ~55.2 MB

// ---------------- edge-index dtype probe (same as round 2, it worked) ----------------
__global__ void k_detect(const int* __restrict__ ei, int* __restrict__ flag) {
    if (blockIdx.x == 0 && threadIdx.x == 0) {
        int odd_zero = 1, any_even = 0;
        for (int i = 0; i < 64; ++i) {
            if (ei[2 * i + 1] != 0) odd_zero = 0;
            if (ei[2 * i] != 0) any_even = 1;
        }
        *flag = (odd_zero && any_even) ? 2 : 1;
    }
}

// ---------------- degree histogram (int) ----------------
__global__ void k_deg(const int* __restrict__ ei, const int* __restrict__ flag,
                      int* __restrict__ deg, int E) {
    int i = blockIdx.x * blockDim.x + threadIdx.x;
    if (i >= E) return;
    int st = *flag;
    int d = ei[(size_t)st * ((size_t)E + i)];
    atomicAdd(&deg[d], 1);
}

// ---------------- exclusive scan of deg -> row_ptr (single block) ----------------
__global__ __launch_bounds__(1024) void k_scan(const int* __restrict__ deg,
                                               int* __restrict__ row_ptr, int N) {
    __shared__ int part[1024];
    const int t = threadIdx.x;
    const int chunk = (N + 1023) >> 10;
    int b = t * chunk, e = min(b + chunk, N);
    int s = 0;
    for (int i = b; i < e; ++i) s += deg[i];
    part[t] = s;
    __syncthreads();
    for (int off = 1; off < 1024; off <<= 1) {
        int v = (t >= off) ? part[t - off] : 0;
        __syncthreads();
        part[t] += v;
        __syncthreads();
    }
    int excl = (t == 0) ? 0 : part[t - 1];
    for (int i = b; i < e; ++i) { row_ptr[i] = excl; excl += deg[i]; }
    if (t == 1023) row_ptr[N] = part[1023];
}

// ---------------- dinv = rsqrt(deg+1) ----------------
__global__ void k_dinv(const int* __restrict__ deg, float* __restrict__ dinv, int N) {
    int i = blockIdx.x * blockDim.x + threadIdx.x;
    if (i < N) dinv[i] = rsqrtf((float)deg[i] + 1.0f);
}

// ---------------- CSR bucket scatter: col[pos] = src ----------------
__global__ void k_scatter(const int* __restrict__ ei, const int* __restrict__ flag,
                          const int* __restrict__ row_ptr, int* __restrict__ fill,
                          int* __restrict__ col, int E) {
    int i = blockIdx.x * blockDim.x + threadIdx.x;
    if (i >= E) return;
    int st = *flag;
    int s = ei[(size_t)st * i];
    int d = ei[(size_t)st * ((size_t)E + i)];
    int pos = row_ptr[d] + atomicAdd(&fill[d], 1);
    col[pos] = s;
}

// ---------------- GEMM1: h[N,128] = x[N,128] @ W1[128,128] (f32) ----------------
__global__ __launch_bounds__(128) void k_gemm1(const float* __restrict__ x,
                                               const float* __restrict__ W,
                                               float* __restrict__ h, int N) {
    __shared__ float xs[4][IN_C];
    const int row0 = blockIdx.x * 4;
    const int c = threadIdx.x;
    #pragma unroll
    for (int r = 0; r < 4; ++r) {
        int rr = row0 + r;
        xs[r][c] = (rr < N) ? x[(size_t)rr * IN_C + c] : 0.0f;
    }
    __syncthreads();
    float acc[4] = {0.f, 0.f, 0.f, 0.f};
    for (int k = 0; k < IN_C; ++k) {
        float w = W[k * HID_C + c];
        #pragma unroll
        for (int r = 0; r < 4; ++r) acc[r] += xs[r][k] * w;
    }
    #pragma unroll
    for (int r = 0; r < 4; ++r) {
        int rr = row0 + r;
        if (rr < N) h[(size_t)rr * HID_C + c] = acc[r];
    }
}

// ---------------- GEMM2: h2[N,64] = relu(agg1[N,128]+b1) @ W2[128,64] ----------------
__global__ __launch_bounds__(256) void k_gemm2(const float* __restrict__ agg1,
                                               const float* __restrict__ b1,
                                               const float* __restrict__ W2,
                                               float* __restrict__ h2, int N) {
    __shared__ float hs[4][HID_C];
    const int row0 = blockIdx.x * 4;
    const int tid = threadIdx.x;
    for (int i = tid; i < 4 * HID_C; i += 256) {
        int r = i >> 7, k = i & 127;
        int rr = row0 + r;
        float v = (rr < N) ? agg1[(size_t)rr * HID_C + k] + b1[k] : 0.0f;
        hs[r][k] = fmaxf(v, 0.0f);
    }
    __syncthreads();
    const int r = tid >> 6;
    const int c = tid & 63;
    float acc = 0.0f;
    for (int k = 0; k < HID_C; ++k)
        acc += hs[r][k] * W2[k * OUT_CC + c];
    int rr = row0 + r;
    if (rr < N) h2[(size_t)rr * OUT_CC + c] = acc;
}

// ---------------- CSR aggregation: one wave per dst node, no atomics ----------------
// out[d] = dinv[d] * ( dinv[d]*feat[d] + sum_e dinv[s_e]*feat[s_e] ) [+ bias]
template <int C>
__global__ __launch_bounds__(256) void k_aggc(const float* __restrict__ feat,
                                              const int* __restrict__ row_ptr,
                                              const int* __restrict__ col,
                                              const float* __restrict__ dinv,
                                              const float* __restrict__ bias,
                                              float* __restrict__ out, int N) {
    const int wave = threadIdx.x >> 6;
    const int lane = threadIdx.x & 63;
    const int node = blockIdx.x * 4 + wave;
    if (node >= N) return;
    const float dd = dinv[node];
    const int beg = row_ptr[node], end = row_ptr[node + 1];

    if (C == 128) {
        const float2* f2 = (const float2*)feat;
        float2 v = f2[(size_t)node * 64 + lane];
        float ax = v.x * dd, ay = v.y * dd;        // self-loop (weight dd applied again at end)
        int e = beg;
        for (; e + 2 <= end; e += 2) {
            int s0 = col[e], s1 = col[e + 1];
            float w0 = dinv[s0], w1 = dinv[s1];
            float2 v0 = f2[(size_t)s0 * 64 + lane];
            float2 v1 = f2[(size_t)s1 * 64 + lane];
            ax += v0.x * w0 + v1.x * w1;
            ay += v0.y * w0 + v1.y * w1;
        }
        if (e < end) {
            int s0 = col[e];
            float w0 = dinv[s0];
            float2 v0 = f2[(size_t)s0 * 64 + lane];
            ax += v0.x * w0;
            ay += v0.y * w0;
        }
        float2 o; o.x = ax * dd; o.y = ay * dd;
        ((float2*)out)[(size_t)node * 64 + lane] = o;
    } else {
        float a = feat[(size_t)node * 64 + lane] * dd;
        int e = beg;
        for (; e + 2 <= end; e += 2) {
            int s0 = col[e], s1 = col[e + 1];
            float w0 = dinv[s0], w1 = dinv[s1];
            float v0 = feat[(size_t)s0 * 64 + lane];
            float v1 = feat[(size_t)s1 * 64 + lane];
            a += v0 * w0 + v1 * w1;
        }
        if (e < end) {
            int s0 = col[e];
            a += feat[(size_t)s0 * 64 + lane] * dinv[s0];
        }
        a *= dd;
        if (bias) a += bias[lane];
        out[(size_t)node * 64 + lane] = a;
    }
}

extern "C" void kernel_launch(void* const* d_in, const int* in_sizes, int n_in,
                              void* d_out, int out_size, void* d_ws, size_t ws_size,
                              hipStream_t stream) {
    const float* x  = (const float*)d_in[0];
    const int*   ei = (const int*)d_in[1];
    const float* W1 = (const float*)d_in[2];
    const float* b1 = (const float*)d_in[3];
    const float* W2 = (const float*)d_in[4];
    const float* b2 = (const float*)d_in[5];

    const int N = in_sizes[0] / IN_C;               // 50000
    const int E = in_sizes[1] / 2;                  // 800000

    char* ws = (char*)d_ws;
    int*   deg     = (int*)(ws + 0);                // reused as fill
    int*   row_ptr = (int*)(ws + 204800);
    float* dinv    = (float*)(ws + 409600);
    int*   col     = (int*)(ws + 614400);
    float* h       = (float*)(ws + 4000000);        // reused as h2
    float* agg1    = (float*)(ws + 29600000);
    int*   flag    = (int*)(ws + 55200000);

    // ---- graph normalization + CSR build ----
    hipMemsetAsync(deg, 0, (size_t)N * 4, stream);
    k_detect<<<1, 64, 0, stream>>>(ei, flag);
    k_deg<<<(E + 255) / 256, 256, 0, stream>>>(ei, flag, deg, E);
    k_scan<<<1, 1024, 0, stream>>>(deg, row_ptr, N);
    k_dinv<<<(N + 255) / 256, 256, 0, stream>>>(deg, dinv, N);
    hipMemsetAsync(deg, 0, (size_t)N * 4, stream);  // deg -> fill counters
    k_scatter<<<(E + 255) / 256, 256, 0, stream>>>(ei, flag, row_ptr, deg, col, E);

    // ---- layer 1 ----
    k_gemm1<<<(N + 3) / 4, 128, 0, stream>>>(x, W1, h, N);
    k_aggc<HID_C><<<(N + 3) / 4, 256, 0, stream>>>(h, row_ptr, col, dinv, nullptr, agg1, N);

    // ---- layer 2 ----
    float* h2 = h;                                   // h dead after agg1
    k_gemm2<<<(N + 3) / 4, 256, 0, stream>>>(agg1, b1, W2, h2, N);
    k_aggc<OUT_CC><<<(N + 3) / 4, 256, 0, stream>>>(h2, row_ptr, col, dinv, b2, (float*)d_out, N);
}

// Round 4
// 375.427 us; speedup vs baseline: 2.0854x; 1.1684x over previous
//
#include <hip/hip_runtime.h>

#define IN_C  128
#define HID_C 128
#define OUT_CC 64

// ---- ws layout (bytes) ----
// deg/fill  int[N]      @ 0
// row_ptr   int[N+1]    @ 204800
// dinv      float[N]    @ 409600
// col       int[E]      @ 614400        (ends 3,814,400)
// bsum      int[256]    @ 3900000
// h         float[N*128]@ 4000000       (reused as h2: float[N*64])
// agg1      float[N*128]@ 29600000
// flag      int         @ 55200000

// ---------------- edge-index dtype probe ----------------
__global__ void k_detect(const int* __restrict__ ei, int* __restrict__ flag) {
    if (blockIdx.x == 0 && threadIdx.x == 0) {
        int odd_zero = 1, any_even = 0;
        for (int i = 0; i < 64; ++i) {
            if (ei[2 * i + 1] != 0) odd_zero = 0;
            if (ei[2 * i] != 0) any_even = 1;
        }
        *flag = (odd_zero && any_even) ? 2 : 1;
    }
}

// ---------------- degree histogram (int) ----------------
__global__ void k_deg(const int* __restrict__ ei, const int* __restrict__ flag,
                      int* __restrict__ deg, int E) {
    int i = blockIdx.x * blockDim.x + threadIdx.x;
    if (i >= E) return;
    int st = *flag;
    int d = ei[(size_t)st * ((size_t)E + i)];
    atomicAdd(&deg[d], 1);
}

// ---------------- hierarchical scan: pass 1, per-block sums ----------------
__global__ __launch_bounds__(256) void k_blocksum(const int* __restrict__ deg,
                                                  int* __restrict__ bsum, int N) {
    __shared__ int s[256];
    int i = blockIdx.x * 256 + threadIdx.x;
    s[threadIdx.x] = (i < N) ? deg[i] : 0;
    __syncthreads();
    for (int off = 128; off > 0; off >>= 1) {
        if (threadIdx.x < off) s[threadIdx.x] += s[threadIdx.x + off];
        __syncthreads();
    }
    if (threadIdx.x == 0) bsum[blockIdx.x] = s[0];
}

// ---------------- pass 2: exclusive scan of block sums (B <= 65536) ----------------
__global__ __launch_bounds__(256) void k_scanbsum(int* __restrict__ bsum, int B) {
    __shared__ int part[256];
    const int t = threadIdx.x;
    const int chunk = (B + 255) >> 8;
    int b = t * chunk, e = min(b + chunk, B);
    int s = 0;
    for (int i = b; i < e; ++i) s += bsum[i];
    part[t] = s;
    __syncthreads();
    for (int off = 1; off < 256; off <<= 1) {
        int v = (t >= off) ? part[t - off] : 0;
        __syncthreads();
        part[t] += v;
        __syncthreads();
    }
    int excl = (t == 0) ? 0 : part[t - 1];
    for (int i = b; i < e; ++i) { int v = bsum[i]; bsum[i] = excl; excl += v; }
}

// ---------------- pass 3: row_ptr + dinv + zero fill (fused) ----------------
__global__ __launch_bounds__(256) void k_rowptr(int* __restrict__ deg,   // zeroed on exit (-> fill)
                                                const int* __restrict__ bsum_excl,
                                                int* __restrict__ row_ptr,
                                                float* __restrict__ dinv, int N) {
    __shared__ int s[256];
    const int i = blockIdx.x * 256 + threadIdx.x;
    const int v = (i < N) ? deg[i] : 0;
    s[threadIdx.x] = v;
    __syncthreads();
    for (int off = 1; off < 256; off <<= 1) {
        int u = (threadIdx.x >= off) ? s[threadIdx.x - off] : 0;
        __syncthreads();
        s[threadIdx.x] += u;
        __syncthreads();
    }
    if (i < N) {
        int incl = bsum_excl[blockIdx.x] + s[threadIdx.x];
        row_ptr[i] = incl - v;                       // exclusive
        dinv[i] = rsqrtf((float)v + 1.0f);           // +1 = self-loop
        deg[i] = 0;                                  // becomes fill counter
        if (i == N - 1) row_ptr[N] = incl;
    }
}

// ---------------- CSR bucket scatter: col[pos] = src ----------------
__global__ void k_scatter(const int* __restrict__ ei, const int* __restrict__ flag,
                          const int* __restrict__ row_ptr, int* __restrict__ fill,
                          int* __restrict__ col, int E) {
    int i = blockIdx.x * blockDim.x + threadIdx.x;
    if (i >= E) return;
    int st = *flag;
    int s = ei[(size_t)st * i];
    int d = ei[(size_t)st * ((size_t)E + i)];
    int pos = row_ptr[d] + atomicAdd(&fill[d], 1);
    col[pos] = s;
}

// ---------------- GEMM1: h[N,128] = x[N,128] @ W1[128,128] (f32) ----------------
__global__ __launch_bounds__(128) void k_gemm1(const float* __restrict__ x,
                                               const float* __restrict__ W,
                                               float* __restrict__ h, int N) {
    __shared__ float xs[4][IN_C];
    const int row0 = blockIdx.x * 4;
    const int c = threadIdx.x;
    #pragma unroll
    for (int r = 0; r < 4; ++r) {
        int rr = row0 + r;
        xs[r][c] = (rr < N) ? x[(size_t)rr * IN_C + c] : 0.0f;
    }
    __syncthreads();
    float acc[4] = {0.f, 0.f, 0.f, 0.f};
    for (int k = 0; k < IN_C; ++k) {
        float w = W[k * HID_C + c];
        #pragma unroll
        for (int r = 0; r < 4; ++r) acc[r] += xs[r][k] * w;
    }
    #pragma unroll
    for (int r = 0; r < 4; ++r) {
        int rr = row0 + r;
        if (rr < N) h[(size_t)rr * HID_C + c] = acc[r];
    }
}

// ---------------- GEMM2: h2[N,64] = relu(agg1[N,128]+b1) @ W2[128,64] ----------------
__global__ __launch_bounds__(256) void k_gemm2(const float* __restrict__ agg1,
                                               const float* __restrict__ b1,
                                               const float* __restrict__ W2,
                                               float* __restrict__ h2, int N) {
    __shared__ float hs[4][HID_C];
    const int row0 = blockIdx.x * 4;
    const int tid = threadIdx.x;
    for (int i = tid; i < 4 * HID_C; i += 256) {
        int r = i >> 7, k = i & 127;
        int rr = row0 + r;
        float v = (rr < N) ? agg1[(size_t)rr * HID_C + k] + b1[k] : 0.0f;
        hs[r][k] = fmaxf(v, 0.0f);
    }
    __syncthreads();
    const int r = tid >> 6;
    const int c = tid & 63;
    float acc = 0.0f;
    for (int k = 0; k < HID_C; ++k)
        acc += hs[r][k] * W2[k * OUT_CC + c];
    int rr = row0 + r;
    if (rr < N) h2[(size_t)rr * OUT_CC + c] = acc;
}

// ---------------- CSR aggregation: one wave per dst node, no atomics ----------------
template <int C>
__global__ __launch_bounds__(256) void k_aggc(const float* __restrict__ feat,
                                              const int* __restrict__ row_ptr,
                                              const int* __restrict__ col,
                                              const float* __restrict__ dinv,
                                              const float* __restrict__ bias,
                                              float* __restrict__ out, int N) {
    const int wave = threadIdx.x >> 6;
    const int lane = threadIdx.x & 63;
    const int node = blockIdx.x * 4 + wave;
    if (node >= N) return;
    const float dd = dinv[node];
    const int beg = row_ptr[node], end = row_ptr[node + 1];

    if (C == 128) {
        const float2* f2 = (const float2*)feat;
        float2 v = f2[(size_t)node * 64 + lane];
        float ax = v.x * dd, ay = v.y * dd;
        int e = beg;
        for (; e + 2 <= end; e += 2) {
            int s0 = col[e], s1 = col[e + 1];
            float w0 = dinv[s0], w1 = dinv[s1];
            float2 v0 = f2[(size_t)s0 * 64 + lane];
            float2 v1 = f2[(size_t)s1 * 64 + lane];
            ax += v0.x * w0 + v1.x * w1;
            ay += v0.y * w0 + v1.y * w1;
        }
        if (e < end) {
            int s0 = col[e];
            float w0 = dinv[s0];
            float2 v0 = f2[(size_t)s0 * 64 + lane];
            ax += v0.x * w0;
            ay += v0.y * w0;
        }
        float2 o; o.x = ax * dd; o.y = ay * dd;
        ((float2*)out)[(size_t)node * 64 + lane] = o;
    } else {
        float a = feat[(size_t)node * 64 + lane] * dd;
        int e = beg;
        for (; e + 2 <= end; e += 2) {
            int s0 = col[e], s1 = col[e + 1];
            float w0 = dinv[s0], w1 = dinv[s1];
            float v0 = feat[(size_t)s0 * 64 + lane];
            float v1 = feat[(size_t)s1 * 64 + lane];
            a += v0 * w0 + v1 * w1;
        }
        if (e < end) {
            int s0 = col[e];
            a += feat[(size_t)s0 * 64 + lane] * dinv[s0];
        }
        a *= dd;
        if (bias) a += bias[lane];
        out[(size_t)node * 64 + lane] = a;
    }
}

extern "C" void kernel_launch(void* const* d_in, const int* in_sizes, int n_in,
                              void* d_out, int out_size, void* d_ws, size_t ws_size,
                              hipStream_t stream) {
    const float* x  = (const float*)d_in[0];
    const int*   ei = (const int*)d_in[1];
    const float* W1 = (const float*)d_in[2];
    const float* b1 = (const float*)d_in[3];
    const float* W2 = (const float*)d_in[4];
    const float* b2 = (const float*)d_in[5];

    const int N = in_sizes[0] / IN_C;               // 50000
    const int E = in_sizes[1] / 2;                  // 800000

    char* ws = (char*)d_ws;
    int*   deg     = (int*)(ws + 0);                // reused as fill
    int*   row_ptr = (int*)(ws + 204800);
    float* dinv    = (float*)(ws + 409600);
    int*   col     = (int*)(ws + 614400);
    int*   bsum    = (int*)(ws + 3900000);
    float* h       = (float*)(ws + 4000000);        // reused as h2
    float* agg1    = (float*)(ws + 29600000);
    int*   flag    = (int*)(ws + 55200000);

    const int NB = (N + 255) / 256;                 // 196 scan blocks

    // ---- graph normalization + CSR build ----
    hipMemsetAsync(deg, 0, (size_t)N * 4, stream);
    k_detect<<<1, 64, 0, stream>>>(ei, flag);
    k_deg<<<(E + 255) / 256, 256, 0, stream>>>(ei, flag, deg, E);
    k_blocksum<<<NB, 256, 0, stream>>>(deg, bsum, N);
    k_scanbsum<<<1, 256, 0, stream>>>(bsum, NB);
    k_rowptr<<<NB, 256, 0, stream>>>(deg, bsum, row_ptr, dinv, N);   // also zeroes fill, computes dinv
    k_scatter<<<(E + 255) / 256, 256, 0, stream>>>(ei, flag, row_ptr, deg, col, E);

    // ---- layer 1 ----
    k_gemm1<<<(N + 3) / 4, 128, 0, stream>>>(x, W1, h, N);
    k_aggc<HID_C><<<(N + 3) / 4, 256, 0, stream>>>(h, row_ptr, col, dinv, nullptr, agg1, N);

    // ---- layer 2 ----
    float* h2 = h;                                   // h dead after agg1
    k_gemm2<<<(N + 3) / 4, 256, 0, stream>>>(agg1, b1, W2, h2, N);
    k_aggc<OUT_CC><<<(N + 3) / 4, 256, 0, stream>>>(h2, row_ptr, col, dinv, b2, (float*)d_out, N);
}

// Round 5
// 323.489 us; speedup vs baseline: 2.4203x; 1.1606x over previous
//
#include <hip/hip_runtime.h>
#include <hip/hip_bf16.h>

#define IN_C  128
#define HID_C 128
#define OUT_CC 64

typedef __hip_bfloat16 bf16;

// unpack a packed bf16x2 dword -> float2 (elem0 = low 16 bits)
__device__ __forceinline__ float2 bf2_to_f2(unsigned int v) {
    float2 r;
    r.x = __uint_as_float(v << 16);
    r.y = __uint_as_float(v & 0xffff0000u);
    return r;
}

// ---- ws layout (bytes) ----
// deg/fill  int[N]        @ 0
// row_ptr   int[N+1]      @ 204800
// dinv      float[N]      @ 409600
// col       int[E]        @ 614400       (ends 3,814,400)
// bsum      int[256]      @ 3900000
// h (bf16)  [N*128]       @ 4000000      (reused as h2 bf16 [N*64])
// agg1 f32  [N*128]       @ 29600000
// flag      int           @ 55200000

// ---------------- edge-index dtype probe ----------------
__global__ void k_detect(const int* __restrict__ ei, int* __restrict__ flag) {
    if (blockIdx.x == 0 && threadIdx.x == 0) {
        int odd_zero = 1, any_even = 0;
        for (int i = 0; i < 64; ++i) {
            if (ei[2 * i + 1] != 0) odd_zero = 0;
            if (ei[2 * i] != 0) any_even = 1;
        }
        *flag = (odd_zero && any_even) ? 2 : 1;
    }
}

// ---------------- degree histogram (int) ----------------
__global__ void k_deg(const int* __restrict__ ei, const int* __restrict__ flag,
                      int* __restrict__ deg, int E) {
    int i = blockIdx.x * blockDim.x + threadIdx.x;
    if (i >= E) return;
    int st = *flag;
    int d = ei[(size_t)st * ((size_t)E + i)];
    atomicAdd(&deg[d], 1);
}

// ---------------- hierarchical scan: pass 1, per-block sums ----------------
__global__ __launch_bounds__(256) void k_blocksum(const int* __restrict__ deg,
                                                  int* __restrict__ bsum, int N) {
    __shared__ int s[256];
    int i = blockIdx.x * 256 + threadIdx.x;
    s[threadIdx.x] = (i < N) ? deg[i] : 0;
    __syncthreads();
    for (int off = 128; off > 0; off >>= 1) {
        if (threadIdx.x < off) s[threadIdx.x] += s[threadIdx.x + off];
        __syncthreads();
    }
    if (threadIdx.x == 0) bsum[blockIdx.x] = s[0];
}

// ---------------- pass 2: exclusive scan of block sums ----------------
__global__ __launch_bounds__(256) void k_scanbsum(int* __restrict__ bsum, int B) {
    __shared__ int part[256];
    const int t = threadIdx.x;
    const int chunk = (B + 255) >> 8;
    int b = t * chunk, e = min(b + chunk, B);
    int s = 0;
    for (int i = b; i < e; ++i) s += bsum[i];
    part[t] = s;
    __syncthreads();
    for (int off = 1; off < 256; off <<= 1) {
        int v = (t >= off) ? part[t - off] : 0;
        __syncthreads();
        part[t] += v;
        __syncthreads();
    }
    int excl = (t == 0) ? 0 : part[t - 1];
    for (int i = b; i < e; ++i) { int v = bsum[i]; bsum[i] = excl; excl += v; }
}

// ---------------- pass 3: row_ptr + dinv + zero fill (fused) ----------------
__global__ __launch_bounds__(256) void k_rowptr(int* __restrict__ deg,
                                                const int* __restrict__ bsum_excl,
                                                int* __restrict__ row_ptr,
                                                float* __restrict__ dinv, int N) {
    __shared__ int s[256];
    const int i = blockIdx.x * 256 + threadIdx.x;
    const int v = (i < N) ? deg[i] : 0;
    s[threadIdx.x] = v;
    __syncthreads();
    for (int off = 1; off < 256; off <<= 1) {
        int u = (threadIdx.x >= off) ? s[threadIdx.x - off] : 0;
        __syncthreads();
        s[threadIdx.x] += u;
        __syncthreads();
    }
    if (i < N) {
        int incl = bsum_excl[blockIdx.x] + s[threadIdx.x];
        row_ptr[i] = incl - v;
        dinv[i] = rsqrtf((float)v + 1.0f);
        deg[i] = 0;
        if (i == N - 1) row_ptr[N] = incl;
    }
}

// ---------------- CSR bucket scatter: col[pos] = src ----------------
__global__ void k_scatter(const int* __restrict__ ei, const int* __restrict__ flag,
                          const int* __restrict__ row_ptr, int* __restrict__ fill,
                          int* __restrict__ col, int E) {
    int i = blockIdx.x * blockDim.x + threadIdx.x;
    if (i >= E) return;
    int st = *flag;
    int s = ei[(size_t)st * i];
    int d = ei[(size_t)st * ((size_t)E + i)];
    int pos = row_ptr[d] + atomicAdd(&fill[d], 1);
    col[pos] = s;
}

// ---------------- GEMM1: h[N,128] = x[N,128] @ W1[128,128], f32 compute, bf16 store ----
__global__ __launch_bounds__(128) void k_gemm1(const float* __restrict__ x,
                                               const float* __restrict__ W,
                                               bf16* __restrict__ h, int N) {
    __shared__ float xs[4][IN_C];
    const int row0 = blockIdx.x * 4;
    const int c = threadIdx.x;
    #pragma unroll
    for (int r = 0; r < 4; ++r) {
        int rr = row0 + r;
        xs[r][c] = (rr < N) ? x[(size_t)rr * IN_C + c] : 0.0f;
    }
    __syncthreads();
    float acc[4] = {0.f, 0.f, 0.f, 0.f};
    for (int k = 0; k < IN_C; ++k) {
        float w = W[k * HID_C + c];
        #pragma unroll
        for (int r = 0; r < 4; ++r) acc[r] += xs[r][k] * w;
    }
    #pragma unroll
    for (int r = 0; r < 4; ++r) {
        int rr = row0 + r;
        if (rr < N) h[(size_t)rr * HID_C + c] = __float2bfloat16(acc[r]);
    }
}

// ---------------- GEMM2: h2[N,64] = relu(agg1[N,128]+b1) @ W2[128,64], bf16 store ----
__global__ __launch_bounds__(256) void k_gemm2(const float* __restrict__ agg1,
                                               const float* __restrict__ b1,
                                               const float* __restrict__ W2,
                                               bf16* __restrict__ h2, int N) {
    __shared__ float hs[4][HID_C];
    const int row0 = blockIdx.x * 4;
    const int tid = threadIdx.x;
    for (int i = tid; i < 4 * HID_C; i += 256) {
        int r = i >> 7, k = i & 127;
        int rr = row0 + r;
        float v = (rr < N) ? agg1[(size_t)rr * HID_C + k] + b1[k] : 0.0f;
        hs[r][k] = fmaxf(v, 0.0f);
    }
    __syncthreads();
    const int r = tid >> 6;
    const int c = tid & 63;
    float acc = 0.0f;
    for (int k = 0; k < HID_C; ++k)
        acc += hs[r][k] * W2[k * OUT_CC + c];
    int rr = row0 + r;
    if (rr < N) h2[(size_t)rr * OUT_CC + c] = __float2bfloat16(acc);
}

// ---------------- agg layer 1: feat = bf16 [N,128] (64 dwords/row), out fp32 ----------------
__global__ __launch_bounds__(256) void k_agg128(const unsigned int* __restrict__ feat,
                                                const int* __restrict__ row_ptr,
                                                const int* __restrict__ col,
                                                const float* __restrict__ dinv,
                                                float* __restrict__ out, int N) {
    const int wave = threadIdx.x >> 6, lane = threadIdx.x & 63;
    const int node = blockIdx.x * 4 + wave;
    if (node >= N) return;
    const float dd = dinv[node];
    const int beg = row_ptr[node], end = row_ptr[node + 1];
    float2 v = bf2_to_f2(feat[(size_t)node * 64 + lane]);   // self-loop
    float ax = v.x * dd, ay = v.y * dd;
    int e = beg;
    for (; e + 4 <= end; e += 4) {
        int s0 = col[e], s1 = col[e + 1], s2 = col[e + 2], s3 = col[e + 3];
        float w0 = dinv[s0], w1 = dinv[s1], w2 = dinv[s2], w3 = dinv[s3];
        float2 v0 = bf2_to_f2(feat[(size_t)s0 * 64 + lane]);
        float2 v1 = bf2_to_f2(feat[(size_t)s1 * 64 + lane]);
        float2 v2 = bf2_to_f2(feat[(size_t)s2 * 64 + lane]);
        float2 v3 = bf2_to_f2(feat[(size_t)s3 * 64 + lane]);
        ax += v0.x * w0 + v1.x * w1 + v2.x * w2 + v3.x * w3;
        ay += v0.y * w0 + v1.y * w1 + v2.y * w2 + v3.y * w3;
    }
    for (; e < end; ++e) {
        int s = col[e];
        float w = dinv[s];
        float2 vv = bf2_to_f2(feat[(size_t)s * 64 + lane]);
        ax += vv.x * w;
        ay += vv.y * w;
    }
    float2 o; o.x = ax * dd; o.y = ay * dd;
    ((float2*)out)[(size_t)node * 64 + lane] = o;
}

// ---------------- agg layer 2: feat = bf16 [N,64] (32 dwords/row), +bias, out fp32 ------
// wave split into two 32-lane halves processing alternate edges; shfl_xor(32) combine.
__global__ __launch_bounds__(256) void k_agg64(const unsigned int* __restrict__ feat,
                                               const int* __restrict__ row_ptr,
                                               const int* __restrict__ col,
                                               const float* __restrict__ dinv,
                                               const float* __restrict__ bias,
                                               float* __restrict__ out, int N) {
    const int wave = threadIdx.x >> 6, lane = threadIdx.x & 63;
    const int half = lane >> 5, l32 = lane & 31;
    const int node = blockIdx.x * 4 + wave;
    if (node >= N) return;
    const float dd = dinv[node];
    const int beg = row_ptr[node], end = row_ptr[node + 1];
    float ax = 0.f, ay = 0.f;
    {
        float2 v = bf2_to_f2(feat[(size_t)node * 32 + l32]);  // self-loop, counted once
        if (half == 0) { ax = v.x * dd; ay = v.y * dd; }
    }
    int e = beg + half;
    for (; e + 2 < end; e += 4) {                             // 2 edges per half per iter
        int sa = col[e], sb = col[e + 2];
        float wa = dinv[sa], wb = dinv[sb];
        float2 va = bf2_to_f2(feat[(size_t)sa * 32 + l32]);
        float2 vb = bf2_to_f2(feat[(size_t)sb * 32 + l32]);
        ax += va.x * wa + vb.x * wb;
        ay += va.y * wa + vb.y * wb;
    }
    if (e < end) {
        int s = col[e];
        float w = dinv[s];
        float2 v = bf2_to_f2(feat[(size_t)s * 32 + l32]);
        ax += v.x * w;
        ay += v.y * w;
    }
    ax += __shfl_xor(ax, 32, 64);
    ay += __shfl_xor(ay, 32, 64);
    if (half == 0) {
        float2 o;
        o.x = ax * dd + bias[2 * l32];
        o.y = ay * dd + bias[2 * l32 + 1];
        ((float2*)out)[(size_t)node * 32 + l32] = o;
    }
}

extern "C" void kernel_launch(void* const* d_in, const int* in_sizes, int n_in,
                              void* d_out, int out_size, void* d_ws, size_t ws_size,
                              hipStream_t stream) {
    const float* x  = (const float*)d_in[0];
    const int*   ei = (const int*)d_in[1];
    const float* W1 = (const float*)d_in[2];
    const float* b1 = (const float*)d_in[3];
    const float* W2 = (const float*)d_in[4];
    const float* b2 = (const float*)d_in[5];

    const int N = in_sizes[0] / IN_C;               // 50000
    const int E = in_sizes[1] / 2;                  // 800000

    char* ws = (char*)d_ws;
    int*   deg     = (int*)(ws + 0);                // reused as fill
    int*   row_ptr = (int*)(ws + 204800);
    float* dinv    = (float*)(ws + 409600);
    int*   col     = (int*)(ws + 614400);
    int*   bsum    = (int*)(ws + 3900000);
    bf16*  h       = (bf16*)(ws + 4000000);         // reused as h2 (bf16 [N,64])
    float* agg1    = (float*)(ws + 29600000);
    int*   flag    = (int*)(ws + 55200000);

    const int NB = (N + 255) / 256;

    // ---- graph normalization + CSR build ----
    hipMemsetAsync(deg, 0, (size_t)N * 4, stream);
    k_detect<<<1, 64, 0, stream>>>(ei, flag);
    k_deg<<<(E + 255) / 256, 256, 0, stream>>>(ei, flag, deg, E);
    k_blocksum<<<NB, 256, 0, stream>>>(deg, bsum, N);
    k_scanbsum<<<1, 256, 0, stream>>>(bsum, NB);
    k_rowptr<<<NB, 256, 0, stream>>>(deg, bsum, row_ptr, dinv, N);
    k_scatter<<<(E + 255) / 256, 256, 0, stream>>>(ei, flag, row_ptr, deg, col, E);

    // ---- layer 1 ----
    k_gemm1<<<(N + 3) / 4, 128, 0, stream>>>(x, W1, h, N);
    k_agg128<<<(N + 3) / 4, 256, 0, stream>>>((const unsigned int*)h, row_ptr, col, dinv, agg1, N);

    // ---- layer 2 ----
    bf16* h2 = h;                                    // h dead after agg1
    k_gemm2<<<(N + 3) / 4, 256, 0, stream>>>(agg1, b1, W2, h2, N);
    k_agg64<<<(N + 3) / 4, 256, 0, stream>>>((const unsigned int*)h2, row_ptr, col, dinv, b2, (float*)d_out, N);
}

// Round 6
// 269.540 us; speedup vs baseline: 2.9047x; 1.2002x over previous
//
#include <hip/hip_runtime.h>
#include <hip/hip_bf16.h>

#define IN_C  128
#define HID_C 128
#define OUT_CC 64

using short8  = __attribute__((ext_vector_type(8))) short;
using float4v = __attribute__((ext_vector_type(4))) float;

// fp32 -> bf16 (round-to-nearest-even, finite inputs)
__device__ __forceinline__ unsigned short f2b(float f) {
    unsigned int u = __float_as_uint(f);
    return (unsigned short)((u + 0x7fffu + ((u >> 16) & 1u)) >> 16);
}
__device__ __forceinline__ unsigned int pack2(float a, float b) {
    return (unsigned int)f2b(a) | ((unsigned int)f2b(b) << 16);
}
// unpack packed bf16x2 dword -> float2 (elem0 = low 16 bits)
__device__ __forceinline__ float2 bf2_to_f2(unsigned int v) {
    float2 r;
    r.x = __uint_as_float(v << 16);
    r.y = __uint_as_float(v & 0xffff0000u);
    return r;
}

// ---- ws layout (bytes) ----
// deg/fill  int[N]        @ 0
// row_ptr   int[N+1]      @ 204800
// dinv      float[N]      @ 409600
// col       int[E]        @ 614400       (ends 3,814,400)
// bsum      int[256]      @ 3900000
// w1frag    bf16[16384]   @ 3904000      (32 KB, MFMA B-frag order)
// w2frag    bf16[8192]    @ 3936768      (16 KB)
// h (bf16)  [N*128]       @ 4000000      (reused as h2 bf16 [N*64])
// agg1 f32  [N*128]       @ 29600000
// flag      int           @ 55200000

// ---------------- edge-index dtype probe ----------------
__global__ void k_detect(const int* __restrict__ ei, int* __restrict__ flag) {
    if (blockIdx.x == 0 && threadIdx.x == 0) {
        int odd_zero = 1, any_even = 0;
        for (int i = 0; i < 64; ++i) {
            if (ei[2 * i + 1] != 0) odd_zero = 0;
            if (ei[2 * i] != 0) any_even = 1;
        }
        *flag = (odd_zero && any_even) ? 2 : 1;
    }
}

// ---------------- degree histogram ----------------
__global__ void k_deg(const int* __restrict__ ei, const int* __restrict__ flag,
                      int* __restrict__ deg, int E) {
    int i = blockIdx.x * blockDim.x + threadIdx.x;
    if (i >= E) return;
    int st = *flag;
    int d = ei[(size_t)st * ((size_t)E + i)];
    atomicAdd(&deg[d], 1);
}

// ---------------- hierarchical scan ----------------
__global__ __launch_bounds__(256) void k_blocksum(const int* __restrict__ deg,
                                                  int* __restrict__ bsum, int N) {
    __shared__ int s[256];
    int i = blockIdx.x * 256 + threadIdx.x;
    s[threadIdx.x] = (i < N) ? deg[i] : 0;
    __syncthreads();
    for (int off = 128; off > 0; off >>= 1) {
        if (threadIdx.x < off) s[threadIdx.x] += s[threadIdx.x + off];
        __syncthreads();
    }
    if (threadIdx.x == 0) bsum[blockIdx.x] = s[0];
}

__global__ __launch_bounds__(256) void k_scanbsum(int* __restrict__ bsum, int B) {
    __shared__ int part[256];
    const int t = threadIdx.x;
    const int chunk = (B + 255) >> 8;
    int b = t * chunk, e = min(b + chunk, B);
    int s = 0;
    for (int i = b; i < e; ++i) s += bsum[i];
    part[t] = s;
    __syncthreads();
    for (int off = 1; off < 256; off <<= 1) {
        int v = (t >= off) ? part[t - off] : 0;
        __syncthreads();
        part[t] += v;
        __syncthreads();
    }
    int excl = (t == 0) ? 0 : part[t - 1];
    for (int i = b; i < e; ++i) { int v = bsum[i]; bsum[i] = excl; excl += v; }
}

__global__ __launch_bounds__(256) void k_rowptr(int* __restrict__ deg,
                                                const int* __restrict__ bsum_excl,
                                                int* __restrict__ row_ptr,
                                                float* __restrict__ dinv, int N) {
    __shared__ int s[256];
    const int i = blockIdx.x * 256 + threadIdx.x;
    const int v = (i < N) ? deg[i] : 0;
    s[threadIdx.x] = v;
    __syncthreads();
    for (int off = 1; off < 256; off <<= 1) {
        int u = (threadIdx.x >= off) ? s[threadIdx.x - off] : 0;
        __syncthreads();
        s[threadIdx.x] += u;
        __syncthreads();
    }
    if (i < N) {
        int incl = bsum_excl[blockIdx.x] + s[threadIdx.x];
        row_ptr[i] = incl - v;
        dinv[i] = rsqrtf((float)v + 1.0f);
        deg[i] = 0;
        if (i == N - 1) row_ptr[N] = incl;
    }
}

// ---------------- CSR bucket scatter ----------------
__global__ void k_scatter(const int* __restrict__ ei, const int* __restrict__ flag,
                          const int* __restrict__ row_ptr, int* __restrict__ fill,
                          int* __restrict__ col, int E) {
    int i = blockIdx.x * blockDim.x + threadIdx.x;
    if (i >= E) return;
    int st = *flag;
    int s = ei[(size_t)st * i];
    int d = ei[(size_t)st * ((size_t)E + i)];
    int pos = row_ptr[d] + atomicAdd(&fill[d], 1);
    col[pos] = s;
}

// ---------------- weight prep: fp32 -> bf16 in MFMA B-frag order ----------------
// frag element index: ((ntile*4 + kstep)*64 + lane)*8 + j
// maps to W[k][n] with k = kstep*32 + (lane>>4)*8 + j, n = ntile*16 + (lane&15)
__global__ __launch_bounds__(256) void k_prepw(const float* __restrict__ W1,
                                               const float* __restrict__ W2,
                                               unsigned short* __restrict__ w1f,
                                               unsigned short* __restrict__ w2f) {
    int e = blockIdx.x * 256 + threadIdx.x;
    if (e < 16384) {                                  // W1: 8 ntiles x 4 ksteps
        int j = e & 7, lane = (e >> 3) & 63, ks = (e >> 9) & 3, nt = e >> 11;
        int k = ks * 32 + ((lane >> 4) << 3) + j;
        int n = nt * 16 + (lane & 15);
        w1f[e] = f2b(W1[k * 128 + n]);
    } else if (e < 16384 + 8192) {                    // W2: 4 ntiles x 4 ksteps
        int e2 = e - 16384;
        int j = e2 & 7, lane = (e2 >> 3) & 63, ks = (e2 >> 9) & 3, nt = e2 >> 11;
        int k = ks * 32 + ((lane >> 4) << 3) + j;
        int n = nt * 16 + (lane & 15);
        w2f[e2] = f2b(W2[k * 64 + n]);
    }
}

// ---------------- MFMA GEMM1: h[N,128] = bf16(x) @ bf16(W1), bf16 store ----------------
// block = 256 thr (4 waves), M-tile 64 rows; LDS A row stride 136 bf16 (16B-aligned, conflict-free)
__global__ __launch_bounds__(256) void k_mg1(const float* __restrict__ x,
                                             const unsigned short* __restrict__ w1f,
                                             unsigned short* __restrict__ h, int N) {
    __shared__ unsigned short lds[64 * 136];
    const int t = threadIdx.x;
    const int row0 = blockIdx.x * 64;
    {   // stage: fp32 -> bf16 into LDS
        int r = t >> 2, cc = (t & 3) * 32;
        int grow = row0 + r;
        unsigned int* dst = (unsigned int*)&lds[r * 136 + cc];
        if (grow < N) {
            const float4* src = (const float4*)(x + (size_t)grow * 128 + cc);
            #pragma unroll
            for (int i = 0; i < 8; ++i) {
                float4 v = src[i];
                dst[2 * i]     = pack2(v.x, v.y);
                dst[2 * i + 1] = pack2(v.z, v.w);
            }
        } else {
            #pragma unroll
            for (int i = 0; i < 16; ++i) dst[i] = 0;
        }
    }
    __syncthreads();
    const int w = t >> 6, lane = t & 63;
    const int quad = lane >> 4, m = lane & 15;
    short8 a[4];
    #pragma unroll
    for (int ks = 0; ks < 4; ++ks)
        a[ks] = *(const short8*)&lds[(w * 16 + m) * 136 + ks * 32 + quad * 8];
    float4v acc[8];
    #pragma unroll
    for (int nt = 0; nt < 8; ++nt) acc[nt] = (float4v){0.f, 0.f, 0.f, 0.f};
    const short8* wf = (const short8*)w1f;
    #pragma unroll
    for (int nt = 0; nt < 8; ++nt)
        #pragma unroll
        for (int ks = 0; ks < 4; ++ks)
            acc[nt] = __builtin_amdgcn_mfma_f32_16x16x32_bf16(a[ks], wf[(nt * 4 + ks) * 64 + lane],
                                                              acc[nt], 0, 0, 0);
    #pragma unroll
    for (int nt = 0; nt < 8; ++nt)
        #pragma unroll
        for (int r = 0; r < 4; ++r) {
            int grow = row0 + w * 16 + quad * 4 + r;       // C/D: col=lane&15, row=quad*4+reg
            if (grow < N) h[(size_t)grow * 128 + nt * 16 + m] = f2b(acc[nt][r]);
        }
}

// ---------------- MFMA GEMM2: h2[N,64] = bf16(relu(agg1+b1)) @ bf16(W2), bf16 store ----
__global__ __launch_bounds__(256) void k_mg2(const float* __restrict__ agg1,
                                             const float* __restrict__ b1,
                                             const unsigned short* __restrict__ w2f,
                                             unsigned short* __restrict__ h2, int N) {
    __shared__ unsigned short lds[64 * 136];
    const int t = threadIdx.x;
    const int row0 = blockIdx.x * 64;
    {   // stage: bias + relu + fp32->bf16
        int r = t >> 2, cc = (t & 3) * 32;
        int grow = row0 + r;
        unsigned int* dst = (unsigned int*)&lds[r * 136 + cc];
        if (grow < N) {
            const float4* src = (const float4*)(agg1 + (size_t)grow * 128 + cc);
            const float4* bsrc = (const float4*)(b1 + cc);
            #pragma unroll
            for (int i = 0; i < 8; ++i) {
                float4 v = src[i], bv = bsrc[i];
                v.x = fmaxf(v.x + bv.x, 0.f);
                v.y = fmaxf(v.y + bv.y, 0.f);
                v.z = fmaxf(v.z + bv.z, 0.f);
                v.w = fmaxf(v.w + bv.w, 0.f);
                dst[2 * i]     = pack2(v.x, v.y);
                dst[2 * i + 1] = pack2(v.z, v.w);
            }
        } else {
            #pragma unroll
            for (int i = 0; i < 16; ++i) dst[i] = 0;
        }
    }
    __syncthreads();
    const int w = t >> 6, lane = t & 63;
    const int quad = lane >> 4, m = lane & 15;
    short8 a[4];
    #pragma unroll
    for (int ks = 0; ks < 4; ++ks)
        a[ks] = *(const short8*)&lds[(w * 16 + m) * 136 + ks * 32 + quad * 8];
    float4v acc[4];
    #pragma unroll
    for (int nt = 0; nt < 4; ++nt) acc[nt] = (float4v){0.f, 0.f, 0.f, 0.f};
    const short8* wf = (const short8*)w2f;
    #pragma unroll
    for (int nt = 0; nt < 4; ++nt)
        #pragma unroll
        for (int ks = 0; ks < 4; ++ks)
            acc[nt] = __builtin_amdgcn_mfma_f32_16x16x32_bf16(a[ks], wf[(nt * 4 + ks) * 64 + lane],
                                                              acc[nt], 0, 0, 0);
    #pragma unroll
    for (int nt = 0; nt < 4; ++nt)
        #pragma unroll
        for (int r = 0; r < 4; ++r) {
            int grow = row0 + w * 16 + quad * 4 + r;
            if (grow < N) h2[(size_t)grow * 64 + nt * 16 + m] = f2b(acc[nt][r]);
        }
}

// ---------------- agg layer 1: feat = bf16 [N,128], out fp32 ----------------
__global__ __launch_bounds__(256) void k_agg128(const unsigned int* __restrict__ feat,
                                                const int* __restrict__ row_ptr,
                                                const int* __restrict__ col,
                                                const float* __restrict__ dinv,
                                                float* __restrict__ out, int N) {
    const int wave = threadIdx.x >> 6, lane = threadIdx.x & 63;
    const int node = blockIdx.x * 4 + wave;
    if (node >= N) return;
    const float dd = dinv[node];
    const int beg = row_ptr[node], end = row_ptr[node + 1];
    float2 v = bf2_to_f2(feat[(size_t)node * 64 + lane]);   // self-loop
    float ax = v.x * dd, ay = v.y * dd;
    int e = beg;
    for (; e + 4 <= end; e += 4) {
        int s0 = col[e], s1 = col[e + 1], s2 = col[e + 2], s3 = col[e + 3];
        float w0 = dinv[s0], w1 = dinv[s1], w2 = dinv[s2], w3 = dinv[s3];
        float2 v0 = bf2_to_f2(feat[(size_t)s0 * 64 + lane]);
        float2 v1 = bf2_to_f2(feat[(size_t)s1 * 64 + lane]);
        float2 v2 = bf2_to_f2(feat[(size_t)s2 * 64 + lane]);
        float2 v3 = bf2_to_f2(feat[(size_t)s3 * 64 + lane]);
        ax += v0.x * w0 + v1.x * w1 + v2.x * w2 + v3.x * w3;
        ay += v0.y * w0 + v1.y * w1 + v2.y * w2 + v3.y * w3;
    }
    for (; e < end; ++e) {
        int s = col[e];
        float w = dinv[s];
        float2 vv = bf2_to_f2(feat[(size_t)s * 64 + lane]);
        ax += vv.x * w;
        ay += vv.y * w;
    }
    float2 o; o.x = ax * dd; o.y = ay * dd;
    ((float2*)out)[(size_t)node * 64 + lane] = o;
}

// ---------------- agg layer 2: feat = bf16 [N,64], +bias, out fp32 ----------------
__global__ __launch_bounds__(256) void k_agg64(const unsigned int* __restrict__ feat,
                                               const int* __restrict__ row_ptr,
                                               const int* __restrict__ col,
                                               const float* __restrict__ dinv,
                                               const float* __restrict__ bias,
                                               float* __restrict__ out, int N) {
    const int wave = threadIdx.x >> 6, lane = threadIdx.x & 63;
    const int half = lane >> 5, l32 = lane & 31;
    const int node = blockIdx.x * 4 + wave;
    if (node >= N) return;
    const float dd = dinv[node];
    const int beg = row_ptr[node], end = row_ptr[node + 1];
    float ax = 0.f, ay = 0.f;
    {
        float2 v = bf2_to_f2(feat[(size_t)node * 32 + l32]);
        if (half == 0) { ax = v.x * dd; ay = v.y * dd; }
    }
    int e = beg + half;
    for (; e + 2 < end; e += 4) {
        int sa = col[e], sb = col[e + 2];
        float wa = dinv[sa], wb = dinv[sb];
        float2 va = bf2_to_f2(feat[(size_t)sa * 32 + l32]);
        float2 vb = bf2_to_f2(feat[(size_t)sb * 32 + l32]);
        ax += va.x * wa + vb.x * wb;
        ay += va.y * wa + vb.y * wb;
    }
    if (e < end) {
        int s = col[e];
        float w = dinv[s];
        float2 v = bf2_to_f2(feat[(size_t)s * 32 + l32]);
        ax += v.x * w;
        ay += v.y * w;
    }
    ax += __shfl_xor(ax, 32, 64);
    ay += __shfl_xor(ay, 32, 64);
    if (half == 0) {
        float2 o;
        o.x = ax * dd + bias[2 * l32];
        o.y = ay * dd + bias[2 * l32 + 1];
        ((float2*)out)[(size_t)node * 32 + l32] = o;
    }
}

extern "C" void kernel_launch(void* const* d_in, const int* in_sizes, int n_in,
                              void* d_out, int out_size, void* d_ws, size_t ws_size,
                              hipStream_t stream) {
    const float* x  = (const float*)d_in[0];
    const int*   ei = (const int*)d_in[1];
    const float* W1 = (const float*)d_in[2];
    const float* b1 = (const float*)d_in[3];
    const float* W2 = (const float*)d_in[4];
    const float* b2 = (const float*)d_in[5];

    const int N = in_sizes[0] / IN_C;               // 50000
    const int E = in_sizes[1] / 2;                  // 800000

    char* ws = (char*)d_ws;
    int*            deg     = (int*)(ws + 0);       // reused as fill
    int*            row_ptr = (int*)(ws + 204800);
    float*          dinv    = (float*)(ws + 409600);
    int*            col     = (int*)(ws + 614400);
    int*            bsum    = (int*)(ws + 3900000);
    unsigned short* w1f     = (unsigned short*)(ws + 3904000);
    unsigned short* w2f     = (unsigned short*)(ws + 3936768);
    unsigned short* h       = (unsigned short*)(ws + 4000000);  // bf16, reused as h2
    float*          agg1    = (float*)(ws + 29600000);
    int*            flag    = (int*)(ws + 55200000);

    const int NB = (N + 255) / 256;

    // ---- weight prep + graph normalization + CSR build ----
    k_prepw<<<96, 256, 0, stream>>>(W1, W2, w1f, w2f);
    hipMemsetAsync(deg, 0, (size_t)N * 4, stream);
    k_detect<<<1, 64, 0, stream>>>(ei, flag);
    k_deg<<<(E + 255) / 256, 256, 0, stream>>>(ei, flag, deg, E);
    k_blocksum<<<NB, 256, 0, stream>>>(deg, bsum, N);
    k_scanbsum<<<1, 256, 0, stream>>>(bsum, NB);
    k_rowptr<<<NB, 256, 0, stream>>>(deg, bsum, row_ptr, dinv, N);
    k_scatter<<<(E + 255) / 256, 256, 0, stream>>>(ei, flag, row_ptr, deg, col, E);

    // ---- layer 1 ----
    k_mg1<<<(N + 63) / 64, 256, 0, stream>>>(x, w1f, h, N);
    k_agg128<<<(N + 3) / 4, 256, 0, stream>>>((const unsigned int*)h, row_ptr, col, dinv, agg1, N);

    // ---- layer 2 ----
    unsigned short* h2 = h;                          // h dead after agg1
    k_mg2<<<(N + 63) / 64, 256, 0, stream>>>(agg1, b1, w2f, h2, N);
    k_agg64<<<(N + 3) / 4, 256, 0, stream>>>((const unsigned int*)h2, row_ptr, col, dinv, b2, (float*)d_out, N);
}

// Round 7
// 221.563 us; speedup vs baseline: 3.5336x; 1.2165x over previous
//
#include <hip/hip_runtime.h>
#include <hip/hip_bf16.h>

#define IN_C  128
#define HID_C 128
#define OUT_CC 64
#define BK    128           // nodes per bucket (dst >> 7)

using short8  = __attribute__((ext_vector_type(8))) short;
using float4v = __attribute__((ext_vector_type(4))) float;

// fp32 -> bf16 (round-to-nearest-even, finite inputs)
__device__ __forceinline__ unsigned short f2b(float f) {
    unsigned int u = __float_as_uint(f);
    return (unsigned short)((u + 0x7fffu + ((u >> 16) & 1u)) >> 16);
}
__device__ __forceinline__ unsigned int pack2(float a, float b) {
    return (unsigned int)f2b(a) | ((unsigned int)f2b(b) << 16);
}
__device__ __forceinline__ float2 bf2_to_f2(unsigned int v) {
    float2 r;
    r.x = __uint_as_float(v << 16);
    r.y = __uint_as_float(v & 0xffff0000u);
    return r;
}

// ---- ws layout (bytes) ----
// flag      int           @ 0
// bcnt      int[391]      @ 64
// bptr      int[392]      @ 2048
// bfill     int[391]      @ 4096
// row_ptr   int[N+1]      @ 8192
// dinv      float[N]      @ 212992
// col       int[E]        @ 413696
// w1frag    bf16[16384]   @ 3620864
// w2frag    bf16[8192]    @ 3653632
// ebuf      int2[E]       @ 3670016
// h (bf16)  [N*128]       @ 10070016    (reused as h2 bf16 [N,64])
// agg1 f32  [N*128]       @ 22870016    (ends ~48.5 MB)

// ---------------- edge-index dtype probe ----------------
__global__ void k_detect(const int* __restrict__ ei, int* __restrict__ flag) {
    if (blockIdx.x == 0 && threadIdx.x == 0) {
        int odd_zero = 1, any_even = 0;
        for (int i = 0; i < 64; ++i) {
            if (ei[2 * i + 1] != 0) odd_zero = 0;
            if (ei[2 * i] != 0) any_even = 1;
        }
        *flag = (odd_zero && any_even) ? 2 : 1;
    }
}

// ---------------- bucket histogram: 391 coarse buckets ----------------
__global__ __launch_bounds__(256) void k_bhist(const int* __restrict__ ei,
                                               const int* __restrict__ flag,
                                               int* __restrict__ bcnt, int E, int NBK) {
    __shared__ int lh[512];
    for (int i = threadIdx.x; i < NBK; i += 256) lh[i] = 0;
    __syncthreads();
    const int st = *flag;
    const int base = blockIdx.x * 2048;
    const int lim = min(base + 2048, E);
    for (int i = base + threadIdx.x; i < lim; i += 256) {
        int d = ei[(size_t)st * ((size_t)E + i)];
        atomicAdd(&lh[d >> 7], 1);
    }
    __syncthreads();
    for (int i = threadIdx.x; i < NBK; i += 256)
        if (lh[i]) atomicAdd(&bcnt[i], lh[i]);
}

// ---------------- scan bucket counts -> bptr, init bfill ----------------
__global__ __launch_bounds__(256) void k_bscan(const int* __restrict__ bcnt,
                                               int* __restrict__ bptr,
                                               int* __restrict__ bfill, int B) {
    __shared__ int part[256];
    const int t = threadIdx.x;
    const int chunk = (B + 255) >> 8;
    int b = t * chunk, e = min(b + chunk, B);
    int s = 0;
    for (int i = b; i < e; ++i) s += bcnt[i];
    part[t] = s;
    __syncthreads();
    for (int off = 1; off < 256; off <<= 1) {
        int v = (t >= off) ? part[t - off] : 0;
        __syncthreads();
        part[t] += v;
        __syncthreads();
    }
    int excl = (t == 0) ? 0 : part[t - 1];
    for (int i = b; i < e; ++i) {
        bptr[i] = excl; bfill[i] = excl;
        excl += bcnt[i];
    }
    if (t == 255) bptr[B] = part[255];
}

// ---------------- partition edges into bucket-grouped (src,dst) pairs ----------------
__global__ __launch_bounds__(256) void k_bpart(const int* __restrict__ ei,
                                               const int* __restrict__ flag,
                                               int* __restrict__ bfill,
                                               int2* __restrict__ ebuf, int E, int NBK) {
    __shared__ int lh[512];
    __shared__ int lbase[512];
    const int t = threadIdx.x;
    for (int i = t; i < NBK; i += 256) lh[i] = 0;
    __syncthreads();
    const int st = *flag;
    const int base = blockIdx.x * 2048;
    int s[8], d[8];
    #pragma unroll
    for (int j = 0; j < 8; ++j) {
        int i = base + j * 256 + t;
        if (i < E) {
            s[j] = ei[(size_t)st * i];
            d[j] = ei[(size_t)st * ((size_t)E + i)];
            atomicAdd(&lh[d[j] >> 7], 1);
        } else d[j] = -1;
    }
    __syncthreads();
    for (int i = t; i < NBK; i += 256) {
        int c = lh[i];
        lbase[i] = c ? atomicAdd(&bfill[i], c) : 0;
        lh[i] = 0;                                   // becomes local rank counter
    }
    __syncthreads();
    #pragma unroll
    for (int j = 0; j < 8; ++j) {
        if (d[j] >= 0) {
            int b = d[j] >> 7;
            int r = atomicAdd(&lh[b], 1);
            ebuf[lbase[b] + r] = make_int2(s[j], d[j]);
        }
    }
}

// ---------------- per-bucket local CSR: row_ptr, dinv, col ----------------
__global__ __launch_bounds__(256) void k_blocal(const int2* __restrict__ ebuf,
                                                const int* __restrict__ bptr,
                                                int* __restrict__ row_ptr,
                                                float* __restrict__ dinv,
                                                int* __restrict__ col, int E, int N) {
    __shared__ int cnt[BK];
    __shared__ int sc[BK];
    __shared__ int off[BK];
    const int t = threadIdx.x;
    const int n0 = blockIdx.x * BK;
    const int beg = bptr[blockIdx.x], end = bptr[blockIdx.x + 1];
    if (t < BK) cnt[t] = 0;
    __syncthreads();
    for (int i = beg + t; i < end; i += 256)
        atomicAdd(&cnt[ebuf[i].y - n0], 1);
    __syncthreads();
    if (t < BK) sc[t] = cnt[t];
    __syncthreads();
    for (int o = 1; o < BK; o <<= 1) {
        int v = (t < BK && t >= o) ? sc[t - o] : 0;
        __syncthreads();
        if (t < BK) sc[t] += v;
        __syncthreads();
    }
    if (t < BK) {
        off[t] = sc[t] - cnt[t];                     // exclusive prefix
        if (n0 + t < N) {
            row_ptr[n0 + t] = beg + off[t];
            dinv[n0 + t] = rsqrtf((float)cnt[t] + 1.0f);
        }
        cnt[t] = 0;                                  // becomes fill counter
    }
    if (blockIdx.x == gridDim.x - 1 && t == 0) row_ptr[N] = E;
    __syncthreads();
    for (int i = beg + t; i < end; i += 256) {
        int2 e = ebuf[i];
        int dl = e.y - n0;
        int p = beg + off[dl] + atomicAdd(&cnt[dl], 1);
        col[p] = e.x;
    }
}

// ---------------- weight prep: fp32 -> bf16 in MFMA B-frag order ----------------
__global__ __launch_bounds__(256) void k_prepw(const float* __restrict__ W1,
                                               const float* __restrict__ W2,
                                               unsigned short* __restrict__ w1f,
                                               unsigned short* __restrict__ w2f) {
    int e = blockIdx.x * 256 + threadIdx.x;
    if (e < 16384) {
        int j = e & 7, lane = (e >> 3) & 63, ks = (e >> 9) & 3, nt = e >> 11;
        int k = ks * 32 + ((lane >> 4) << 3) + j;
        int n = nt * 16 + (lane & 15);
        w1f[e] = f2b(W1[k * 128 + n]);
    } else if (e < 16384 + 8192) {
        int e2 = e - 16384;
        int j = e2 & 7, lane = (e2 >> 3) & 63, ks = (e2 >> 9) & 3, nt = e2 >> 11;
        int k = ks * 32 + ((lane >> 4) << 3) + j;
        int n = nt * 16 + (lane & 15);
        w2f[e2] = f2b(W2[k * 64 + n]);
    }
}

// ---------------- MFMA GEMM1 ----------------
__global__ __launch_bounds__(256) void k_mg1(const float* __restrict__ x,
                                             const unsigned short* __restrict__ w1f,
                                             unsigned short* __restrict__ h, int N) {
    __shared__ unsigned short lds[64 * 136];
    const int t = threadIdx.x;
    const int row0 = blockIdx.x * 64;
    {
        int r = t >> 2, cc = (t & 3) * 32;
        int grow = row0 + r;
        unsigned int* dst = (unsigned int*)&lds[r * 136 + cc];
        if (grow < N) {
            const float4* src = (const float4*)(x + (size_t)grow * 128 + cc);
            #pragma unroll
            for (int i = 0; i < 8; ++i) {
                float4 v = src[i];
                dst[2 * i]     = pack2(v.x, v.y);
                dst[2 * i + 1] = pack2(v.z, v.w);
            }
        } else {
            #pragma unroll
            for (int i = 0; i < 16; ++i) dst[i] = 0;
        }
    }
    __syncthreads();
    const int w = t >> 6, lane = t & 63;
    const int quad = lane >> 4, m = lane & 15;
    short8 a[4];
    #pragma unroll
    for (int ks = 0; ks < 4; ++ks)
        a[ks] = *(const short8*)&lds[(w * 16 + m) * 136 + ks * 32 + quad * 8];
    float4v acc[8];
    #pragma unroll
    for (int nt = 0; nt < 8; ++nt) acc[nt] = (float4v){0.f, 0.f, 0.f, 0.f};
    const short8* wf = (const short8*)w1f;
    #pragma unroll
    for (int nt = 0; nt < 8; ++nt)
        #pragma unroll
        for (int ks = 0; ks < 4; ++ks)
            acc[nt] = __builtin_amdgcn_mfma_f32_16x16x32_bf16(a[ks], wf[(nt * 4 + ks) * 64 + lane],
                                                              acc[nt], 0, 0, 0);
    #pragma unroll
    for (int nt = 0; nt < 8; ++nt)
        #pragma unroll
        for (int r = 0; r < 4; ++r) {
            int grow = row0 + w * 16 + quad * 4 + r;
            if (grow < N) h[(size_t)grow * 128 + nt * 16 + m] = f2b(acc[nt][r]);
        }
}

// ---------------- MFMA GEMM2 (bias+ReLU fused into staging) ----------------
__global__ __launch_bounds__(256) void k_mg2(const float* __restrict__ agg1,
                                             const float* __restrict__ b1,
                                             const unsigned short* __restrict__ w2f,
                                             unsigned short* __restrict__ h2, int N) {
    __shared__ unsigned short lds[64 * 136];
    const int t = threadIdx.x;
    const int row0 = blockIdx.x * 64;
    {
        int r = t >> 2, cc = (t & 3) * 32;
        int grow = row0 + r;
        unsigned int* dst = (unsigned int*)&lds[r * 136 + cc];
        if (grow < N) {
            const float4* src = (const float4*)(agg1 + (size_t)grow * 128 + cc);
            const float4* bsrc = (const float4*)(b1 + cc);
            #pragma unroll
            for (int i = 0; i < 8; ++i) {
                float4 v = src[i], bv = bsrc[i];
                v.x = fmaxf(v.x + bv.x, 0.f);
                v.y = fmaxf(v.y + bv.y, 0.f);
                v.z = fmaxf(v.z + bv.z, 0.f);
                v.w = fmaxf(v.w + bv.w, 0.f);
                dst[2 * i]     = pack2(v.x, v.y);
                dst[2 * i + 1] = pack2(v.z, v.w);
            }
        } else {
            #pragma unroll
            for (int i = 0; i < 16; ++i) dst[i] = 0;
        }
    }
    __syncthreads();
    const int w = t >> 6, lane = t & 63;
    const int quad = lane >> 4, m = lane & 15;
    short8 a[4];
    #pragma unroll
    for (int ks = 0; ks < 4; ++ks)
        a[ks] = *(const short8*)&lds[(w * 16 + m) * 136 + ks * 32 + quad * 8];
    float4v acc[4];
    #pragma unroll
    for (int nt = 0; nt < 4; ++nt) acc[nt] = (float4v){0.f, 0.f, 0.f, 0.f};
    const short8* wf = (const short8*)w2f;
    #pragma unroll
    for (int nt = 0; nt < 4; ++nt)
        #pragma unroll
        for (int ks = 0; ks < 4; ++ks)
            acc[nt] = __builtin_amdgcn_mfma_f32_16x16x32_bf16(a[ks], wf[(nt * 4 + ks) * 64 + lane],
                                                              acc[nt], 0, 0, 0);
    #pragma unroll
    for (int nt = 0; nt < 4; ++nt)
        #pragma unroll
        for (int r = 0; r < 4; ++r) {
            int grow = row0 + w * 16 + quad * 4 + r;
            if (grow < N) h2[(size_t)grow * 64 + nt * 16 + m] = f2b(acc[nt][r]);
        }
}

// ---------------- agg layer 1: feat = bf16 [N,128], out fp32 ----------------
__global__ __launch_bounds__(256) void k_agg128(const unsigned int* __restrict__ feat,
                                                const int* __restrict__ row_ptr,
                                                const int* __restrict__ col,
                                                const float* __restrict__ dinv,
                                                float* __restrict__ out, int N) {
    const int wave = threadIdx.x >> 6, lane = threadIdx.x & 63;
    const int node = blockIdx.x * 4 + wave;
    if (node >= N) return;
    const float dd = dinv[node];
    const int beg = row_ptr[node], end = row_ptr[node + 1];
    float2 v = bf2_to_f2(feat[(size_t)node * 64 + lane]);
    float ax = v.x * dd, ay = v.y * dd;
    int e = beg;
    for (; e + 4 <= end; e += 4) {
        int s0 = col[e], s1 = col[e + 1], s2 = col[e + 2], s3 = col[e + 3];
        float w0 = dinv[s0], w1 = dinv[s1], w2 = dinv[s2], w3 = dinv[s3];
        float2 v0 = bf2_to_f2(feat[(size_t)s0 * 64 + lane]);
        float2 v1 = bf2_to_f2(feat[(size_t)s1 * 64 + lane]);
        float2 v2 = bf2_to_f2(feat[(size_t)s2 * 64 + lane]);
        float2 v3 = bf2_to_f2(feat[(size_t)s3 * 64 + lane]);
        ax += v0.x * w0 + v1.x * w1 + v2.x * w2 + v3.x * w3;
        ay += v0.y * w0 + v1.y * w1 + v2.y * w2 + v3.y * w3;
    }
    for (; e < end; ++e) {
        int s = col[e];
        float w = dinv[s];
        float2 vv = bf2_to_f2(feat[(size_t)s * 64 + lane]);
        ax += vv.x * w;
        ay += vv.y * w;
    }
    float2 o; o.x = ax * dd; o.y = ay * dd;
    ((float2*)out)[(size_t)node * 64 + lane] = o;
}

// ---------------- agg layer 2: feat = bf16 [N,64], +bias, out fp32 ----------------
__global__ __launch_bounds__(256) void k_agg64(const unsigned int* __restrict__ feat,
                                               const int* __restrict__ row_ptr,
                                               const int* __restrict__ col,
                                               const float* __restrict__ dinv,
                                               const float* __restrict__ bias,
                                               float* __restrict__ out, int N) {
    const int wave = threadIdx.x >> 6, lane = threadIdx.x & 63;
    const int half = lane >> 5, l32 = lane & 31;
    const int node = blockIdx.x * 4 + wave;
    if (node >= N) return;
    const float dd = dinv[node];
    const int beg = row_ptr[node], end = row_ptr[node + 1];
    float ax = 0.f, ay = 0.f;
    {
        float2 v = bf2_to_f2(feat[(size_t)node * 32 + l32]);
        if (half == 0) { ax = v.x * dd; ay = v.y * dd; }
    }
    int e = beg + half;
    for (; e + 2 < end; e += 4) {
        int sa = col[e], sb = col[e + 2];
        float wa = dinv[sa], wb = dinv[sb];
        float2 va = bf2_to_f2(feat[(size_t)sa * 32 + l32]);
        float2 vb = bf2_to_f2(feat[(size_t)sb * 32 + l32]);
        ax += va.x * wa + vb.x * wb;
        ay += va.y * wa + vb.y * wb;
    }
    if (e < end) {
        int s = col[e];
        float w = dinv[s];
        float2 v = bf2_to_f2(feat[(size_t)s * 32 + l32]);
        ax += v.x * w;
        ay += v.y * w;
    }
    ax += __shfl_xor(ax, 32, 64);
    ay += __shfl_xor(ay, 32, 64);
    if (half == 0) {
        float2 o;
        o.x = ax * dd + bias[2 * l32];
        o.y = ay * dd + bias[2 * l32 + 1];
        ((float2*)out)[(size_t)node * 32 + l32] = o;
    }
}

extern "C" void kernel_launch(void* const* d_in, const int* in_sizes, int n_in,
                              void* d_out, int out_size, void* d_ws, size_t ws_size,
                              hipStream_t stream) {
    const float* x  = (const float*)d_in[0];
    const int*   ei = (const int*)d_in[1];
    const float* W1 = (const float*)d_in[2];
    const float* b1 = (const float*)d_in[3];
    const float* W2 = (const float*)d_in[4];
    const float* b2 = (const float*)d_in[5];

    const int N = in_sizes[0] / IN_C;               // 50000
    const int E = in_sizes[1] / 2;                  // 800000
    const int NBK  = (N + BK - 1) / BK;             // 391 buckets
    const int NCHK = (E + 2047) / 2048;             // 391 edge chunks

    char* ws = (char*)d_ws;
    int*            flag    = (int*)(ws + 0);
    int*            bcnt    = (int*)(ws + 64);
    int*            bptr    = (int*)(ws + 2048);
    int*            bfill   = (int*)(ws + 4096);
    int*            row_ptr = (int*)(ws + 8192);
    float*          dinv    = (float*)(ws + 212992);
    int*            col     = (int*)(ws + 413696);
    unsigned short* w1f     = (unsigned short*)(ws + 3620864);
    unsigned short* w2f     = (unsigned short*)(ws + 3653632);
    int2*           ebuf    = (int2*)(ws + 3670016);
    unsigned short* h       = (unsigned short*)(ws + 10070016); // bf16, reused as h2
    float*          agg1    = (float*)(ws + 22870016);

    // ---- weight prep + CSR build (bucketed, write-local) ----
    k_prepw<<<96, 256, 0, stream>>>(W1, W2, w1f, w2f);
    hipMemsetAsync(bcnt, 0, (size_t)NBK * 4, stream);
    k_detect<<<1, 64, 0, stream>>>(ei, flag);
    k_bhist<<<NCHK, 256, 0, stream>>>(ei, flag, bcnt, E, NBK);
    k_bscan<<<1, 256, 0, stream>>>(bcnt, bptr, bfill, NBK);
    k_bpart<<<NCHK, 256, 0, stream>>>(ei, flag, bfill, ebuf, E, NBK);
    k_blocal<<<NBK, 256, 0, stream>>>(ebuf, bptr, row_ptr, dinv, col, E, N);

    // ---- layer 1 ----
    k_mg1<<<(N + 63) / 64, 256, 0, stream>>>(x, w1f, h, N);
    k_agg128<<<(N + 3) / 4, 256, 0, stream>>>((const unsigned int*)h, row_ptr, col, dinv, agg1, N);

    // ---- layer 2 ----
    unsigned short* h2 = h;                          // h dead after agg1
    k_mg2<<<(N + 63) / 64, 256, 0, stream>>>(agg1, b1, w2f, h2, N);
    k_agg64<<<(N + 3) / 4, 256, 0, stream>>>((const unsigned int*)h2, row_ptr, col, dinv, b2, (float*)d_out, N);
}

// Round 8
// 207.171 us; speedup vs baseline: 3.7791x; 1.0695x over previous
//
#include <hip/hip_runtime.h>
#include <hip/hip_bf16.h>

#define IN_C  128
#define HID_C 128
#define OUT_CC 64
#define BK    128           // nodes per bucket (dst >> 7)

using short8  = __attribute__((ext_vector_type(8))) short;
using float4v = __attribute__((ext_vector_type(4))) float;

// fp32 -> bf16 (round-to-nearest-even, finite inputs)
__device__ __forceinline__ unsigned short f2b(float f) {
    unsigned int u = __float_as_uint(f);
    return (unsigned short)((u + 0x7fffu + ((u >> 16) & 1u)) >> 16);
}
__device__ __forceinline__ unsigned int pack2(float a, float b) {
    return (unsigned int)f2b(a) | ((unsigned int)f2b(b) << 16);
}
__device__ __forceinline__ float2 bf2_to_f2(unsigned int v) {
    float2 r;
    r.x = __uint_as_float(v << 16);
    r.y = __uint_as_float(v & 0xffff0000u);
    return r;
}

// ---- ws layout (bytes) ----
// flag      int           @ 0
// bcnt      int[391]      @ 64
// bptr      int[392]      @ 2048
// bfill     int[391]      @ 4096
// row_ptr   int[N+1]      @ 8192
// dinv      float[N]      @ 212992
// col       int[E]        @ 413696
// w1frag    bf16[16384]   @ 3620864
// w2frag    bf16[8192]    @ 3653632
// ebuf      int2[E]       @ 3670016     (ends 10,070,016)
// h (bf16)  [N*128]       @ 10070016    (reused as h2 bf16 [N,64] after agg128e)
// h1b(bf16) [N*128]       @ 22870016    (ends ~35.7 MB)

// ---------------- setup: weight prep + edge dtype probe + bcnt zero ----------------
__global__ __launch_bounds__(256) void k_setup(const float* __restrict__ W1,
                                               const float* __restrict__ W2,
                                               const int* __restrict__ ei,
                                               unsigned short* __restrict__ w1f,
                                               unsigned short* __restrict__ w2f,
                                               int* __restrict__ flag,
                                               int* __restrict__ bcnt, int NBK) {
    int e = blockIdx.x * 256 + threadIdx.x;
    if (e < 16384) {                                  // W1: frag ((nt*4+ks)*64+lane)*8+j
        int j = e & 7, lane = (e >> 3) & 63, ks = (e >> 9) & 3, nt = e >> 11;
        int k = ks * 32 + ((lane >> 4) << 3) + j;
        int n = nt * 16 + (lane & 15);
        w1f[e] = f2b(W1[k * 128 + n]);
    } else if (e < 16384 + 8192) {
        int e2 = e - 16384;
        int j = e2 & 7, lane = (e2 >> 3) & 63, ks = (e2 >> 9) & 3, nt = e2 >> 11;
        int k = ks * 32 + ((lane >> 4) << 3) + j;
        int n = nt * 16 + (lane & 15);
        w2f[e2] = f2b(W2[k * 64 + n]);
    }
    if (blockIdx.x == 0) {
        for (int i = threadIdx.x; i < NBK; i += 256) bcnt[i] = 0;
        if (threadIdx.x == 0) {
            int odd_zero = 1, any_even = 0;
            for (int i = 0; i < 64; ++i) {
                if (ei[2 * i + 1] != 0) odd_zero = 0;
                if (ei[2 * i] != 0) any_even = 1;
            }
            *flag = (odd_zero && any_even) ? 2 : 1;
        }
    }
}

// ---------------- bucket histogram: NBK coarse buckets ----------------
__global__ __launch_bounds__(256) void k_bhist(const int* __restrict__ ei,
                                               const int* __restrict__ flag,
                                               int* __restrict__ bcnt, int E, int NBK) {
    __shared__ int lh[512];
    for (int i = threadIdx.x; i < NBK; i += 256) lh[i] = 0;
    __syncthreads();
    const int st = *flag;
    const int base = blockIdx.x * 2048;
    const int lim = min(base + 2048, E);
    for (int i = base + threadIdx.x; i < lim; i += 256) {
        int d = ei[(size_t)st * ((size_t)E + i)];
        atomicAdd(&lh[d >> 7], 1);
    }
    __syncthreads();
    for (int i = threadIdx.x; i < NBK; i += 256)
        if (lh[i]) atomicAdd(&bcnt[i], lh[i]);
}

// ---------------- scan bucket counts -> bptr, init bfill ----------------
__global__ __launch_bounds__(256) void k_bscan(const int* __restrict__ bcnt,
                                               int* __restrict__ bptr,
                                               int* __restrict__ bfill, int B) {
    __shared__ int part[256];
    const int t = threadIdx.x;
    const int chunk = (B + 255) >> 8;
    int b = t * chunk, e = min(b + chunk, B);
    int s = 0;
    for (int i = b; i < e; ++i) s += bcnt[i];
    part[t] = s;
    __syncthreads();
    for (int off = 1; off < 256; off <<= 1) {
        int v = (t >= off) ? part[t - off] : 0;
        __syncthreads();
        part[t] += v;
        __syncthreads();
    }
    int excl = (t == 0) ? 0 : part[t - 1];
    for (int i = b; i < e; ++i) {
        bptr[i] = excl; bfill[i] = excl;
        excl += bcnt[i];
    }
    if (t == 255) bptr[B] = part[255];
}

// ---------------- partition edges into bucket-grouped (src,dst) pairs ----------------
__global__ __launch_bounds__(256) void k_bpart(const int* __restrict__ ei,
                                               const int* __restrict__ flag,
                                               int* __restrict__ bfill,
                                               int2* __restrict__ ebuf, int E, int NBK) {
    __shared__ int lh[512];
    __shared__ int lbase[512];
    const int t = threadIdx.x;
    for (int i = t; i < NBK; i += 256) lh[i] = 0;
    __syncthreads();
    const int st = *flag;
    const int base = blockIdx.x * 2048;
    int s[8], d[8];
    #pragma unroll
    for (int j = 0; j < 8; ++j) {
        int i = base + j * 256 + t;
        if (i < E) {
            s[j] = ei[(size_t)st * i];
            d[j] = ei[(size_t)st * ((size_t)E + i)];
            atomicAdd(&lh[d[j] >> 7], 1);
        } else d[j] = -1;
    }
    __syncthreads();
    for (int i = t; i < NBK; i += 256) {
        int c = lh[i];
        lbase[i] = c ? atomicAdd(&bfill[i], c) : 0;
        lh[i] = 0;                                   // becomes local rank counter
    }
    __syncthreads();
    #pragma unroll
    for (int j = 0; j < 8; ++j) {
        if (d[j] >= 0) {
            int b = d[j] >> 7;
            int r = atomicAdd(&lh[b], 1);
            ebuf[lbase[b] + r] = make_int2(s[j], d[j]);
        }
    }
}

// ---------------- fused: per-bucket local CSR (blocks < NBK) | MFMA GEMM1 (rest) ----
__global__ __launch_bounds__(256) void k_blmg1(const int2* __restrict__ ebuf,
                                               const int* __restrict__ bptr,
                                               int* __restrict__ row_ptr,
                                               float* __restrict__ dinv,
                                               int* __restrict__ col,
                                               const float* __restrict__ x,
                                               const unsigned short* __restrict__ w1f,
                                               unsigned short* __restrict__ h,
                                               int E, int N, int NBK) {
    __shared__ unsigned short lds[64 * 136];          // 17.4 KB, shared by both paths
    const int t = threadIdx.x;

    if ((int)blockIdx.x < NBK) {
        // ---- per-bucket CSR build ----
        int* cnt = (int*)lds;
        int* sc  = cnt + BK;
        int* off = sc + BK;
        const int n0 = blockIdx.x * BK;
        const int beg = bptr[blockIdx.x], end = bptr[blockIdx.x + 1];
        if (t < BK) cnt[t] = 0;
        __syncthreads();
        for (int i = beg + t; i < end; i += 256)
            atomicAdd(&cnt[ebuf[i].y - n0], 1);
        __syncthreads();
        if (t < BK) sc[t] = cnt[t];
        __syncthreads();
        for (int o = 1; o < BK; o <<= 1) {
            int v = (t < BK && t >= o) ? sc[t - o] : 0;
            __syncthreads();
            if (t < BK) sc[t] += v;
            __syncthreads();
        }
        if (t < BK) {
            off[t] = sc[t] - cnt[t];
            if (n0 + t < N) {
                row_ptr[n0 + t] = beg + off[t];
                dinv[n0 + t] = rsqrtf((float)cnt[t] + 1.0f);
            }
            cnt[t] = 0;
        }
        if ((int)blockIdx.x == NBK - 1 && t == 0) row_ptr[N] = E;
        __syncthreads();
        for (int i = beg + t; i < end; i += 256) {
            int2 e = ebuf[i];
            int dl = e.y - n0;
            int p = beg + off[dl] + atomicAdd(&cnt[dl], 1);
            col[p] = e.x;
        }
        return;
    }

    // ---- MFMA GEMM1 tile ----
    const int row0 = ((int)blockIdx.x - NBK) * 64;
    {
        int r = t >> 2, cc = (t & 3) * 32;
        int grow = row0 + r;
        unsigned int* dst = (unsigned int*)&lds[r * 136 + cc];
        if (grow < N) {
            const float4* src = (const float4*)(x + (size_t)grow * 128 + cc);
            #pragma unroll
            for (int i = 0; i < 8; ++i) {
                float4 v = src[i];
                dst[2 * i]     = pack2(v.x, v.y);
                dst[2 * i + 1] = pack2(v.z, v.w);
            }
        } else {
            #pragma unroll
            for (int i = 0; i < 16; ++i) dst[i] = 0;
        }
    }
    __syncthreads();
    const int w = t >> 6, lane = t & 63;
    const int quad = lane >> 4, m = lane & 15;
    short8 a[4];
    #pragma unroll
    for (int ks = 0; ks < 4; ++ks)
        a[ks] = *(const short8*)&lds[(w * 16 + m) * 136 + ks * 32 + quad * 8];
    float4v acc[8];
    #pragma unroll
    for (int nt = 0; nt < 8; ++nt) acc[nt] = (float4v){0.f, 0.f, 0.f, 0.f};
    const short8* wf = (const short8*)w1f;
    #pragma unroll
    for (int nt = 0; nt < 8; ++nt)
        #pragma unroll
        for (int ks = 0; ks < 4; ++ks)
            acc[nt] = __builtin_amdgcn_mfma_f32_16x16x32_bf16(a[ks], wf[(nt * 4 + ks) * 64 + lane],
                                                              acc[nt], 0, 0, 0);
    #pragma unroll
    for (int nt = 0; nt < 8; ++nt)
        #pragma unroll
        for (int r = 0; r < 4; ++r) {
            int grow = row0 + w * 16 + quad * 4 + r;   // C/D: col=lane&15, row=quad*4+reg
            if (grow < N) h[(size_t)grow * 128 + nt * 16 + m] = f2b(acc[nt][r]);
        }
}

// ---------------- agg layer 1 + bias + ReLU + bf16: h1b = bf16(relu(Ah + b1)) ----------
__global__ __launch_bounds__(256) void k_agg128e(const unsigned int* __restrict__ feat,
                                                 const int* __restrict__ row_ptr,
                                                 const int* __restrict__ col,
                                                 const float* __restrict__ dinv,
                                                 const float* __restrict__ b1,
                                                 unsigned int* __restrict__ h1b, int N) {
    const int wave = threadIdx.x >> 6, lane = threadIdx.x & 63;
    const int node = blockIdx.x * 4 + wave;
    if (node >= N) return;
    const float dd = dinv[node];
    const int beg = row_ptr[node], end = row_ptr[node + 1];
    float2 v = bf2_to_f2(feat[(size_t)node * 64 + lane]);   // self-loop
    float ax = v.x * dd, ay = v.y * dd;
    int e = beg;
    for (; e + 4 <= end; e += 4) {
        int s0 = col[e], s1 = col[e + 1], s2 = col[e + 2], s3 = col[e + 3];
        float w0 = dinv[s0], w1 = dinv[s1], w2 = dinv[s2], w3 = dinv[s3];
        float2 v0 = bf2_to_f2(feat[(size_t)s0 * 64 + lane]);
        float2 v1 = bf2_to_f2(feat[(size_t)s1 * 64 + lane]);
        float2 v2 = bf2_to_f2(feat[(size_t)s2 * 64 + lane]);
        float2 v3 = bf2_to_f2(feat[(size_t)s3 * 64 + lane]);
        ax += v0.x * w0 + v1.x * w1 + v2.x * w2 + v3.x * w3;
        ay += v0.y * w0 + v1.y * w1 + v2.y * w2 + v3.y * w3;
    }
    for (; e < end; ++e) {
        int s = col[e];
        float w = dinv[s];
        float2 vv = bf2_to_f2(feat[(size_t)s * 64 + lane]);
        ax += vv.x * w;
        ay += vv.y * w;
    }
    float2 b = ((const float2*)b1)[lane];                   // b1[2l], b1[2l+1]
    float ox = fmaxf(ax * dd + b.x, 0.0f);
    float oy = fmaxf(ay * dd + b.y, 0.0f);
    h1b[(size_t)node * 64 + lane] = pack2(ox, oy);
}

// ---------------- MFMA GEMM2: h2[N,64] = h1b(bf16) @ bf16(W2), bf16 store ----------------
__global__ __launch_bounds__(256) void k_mg2(const unsigned int* __restrict__ h1b,
                                             const unsigned short* __restrict__ w2f,
                                             unsigned short* __restrict__ h2, int N) {
    __shared__ unsigned short lds[64 * 136];
    const int t = threadIdx.x;
    const int row0 = blockIdx.x * 64;
    {   // stage: straight bf16 copy (bias+relu already applied)
        int r = t >> 2, cc = (t & 3) * 32;
        int grow = row0 + r;
        uint4* dst = (uint4*)&lds[r * 136 + cc];
        if (grow < N) {
            const uint4* src = (const uint4*)(h1b + (size_t)grow * 64 + (cc >> 1));
            #pragma unroll
            for (int i = 0; i < 4; ++i) dst[i] = src[i];
        } else {
            #pragma unroll
            for (int i = 0; i < 4; ++i) dst[i] = (uint4){0, 0, 0, 0};
        }
    }
    __syncthreads();
    const int w = t >> 6, lane = t & 63;
    const int quad = lane >> 4, m = lane & 15;
    short8 a[4];
    #pragma unroll
    for (int ks = 0; ks < 4; ++ks)
        a[ks] = *(const short8*)&lds[(w * 16 + m) * 136 + ks * 32 + quad * 8];
    float4v acc[4];
    #pragma unroll
    for (int nt = 0; nt < 4; ++nt) acc[nt] = (float4v){0.f, 0.f, 0.f, 0.f};
    const short8* wf = (const short8*)w2f;
    #pragma unroll
    for (int nt = 0; nt < 4; ++nt)
        #pragma unroll
        for (int ks = 0; ks < 4; ++ks)
            acc[nt] = __builtin_amdgcn_mfma_f32_16x16x32_bf16(a[ks], wf[(nt * 4 + ks) * 64 + lane],
                                                              acc[nt], 0, 0, 0);
    #pragma unroll
    for (int nt = 0; nt < 4; ++nt)
        #pragma unroll
        for (int r = 0; r < 4; ++r) {
            int grow = row0 + w * 16 + quad * 4 + r;
            if (grow < N) h2[(size_t)grow * 64 + nt * 16 + m] = f2b(acc[nt][r]);
        }
}

// ---------------- agg layer 2: feat = bf16 [N,64], +b2, out fp32 ----------------
__global__ __launch_bounds__(256) void k_agg64(const unsigned int* __restrict__ feat,
                                               const int* __restrict__ row_ptr,
                                               const int* __restrict__ col,
                                               const float* __restrict__ dinv,
                                               const float* __restrict__ bias,
                                               float* __restrict__ out, int N) {
    const int wave = threadIdx.x >> 6, lane = threadIdx.x & 63;
    const int half = lane >> 5, l32 = lane & 31;
    const int node = blockIdx.x * 4 + wave;
    if (node >= N) return;
    const float dd = dinv[node];
    const int beg = row_ptr[node], end = row_ptr[node + 1];
    float ax = 0.f, ay = 0.f;
    {
        float2 v = bf2_to_f2(feat[(size_t)node * 32 + l32]);
        if (half == 0) { ax = v.x * dd; ay = v.y * dd; }
    }
    int e = beg + half;
    for (; e + 2 < end; e += 4) {
        int sa = col[e], sb = col[e + 2];
        float wa = dinv[sa], wb = dinv[sb];
        float2 va = bf2_to_f2(feat[(size_t)sa * 32 + l32]);
        float2 vb = bf2_to_f2(feat[(size_t)sb * 32 + l32]);
        ax += va.x * wa + vb.x * wb;
        ay += va.y * wa + vb.y * wb;
    }
    if (e < end) {
        int s = col[e];
        float w = dinv[s];
        float2 v = bf2_to_f2(feat[(size_t)s * 32 + l32]);
        ax += v.x * w;
        ay += v.y * w;
    }
    ax += __shfl_xor(ax, 32, 64);
    ay += __shfl_xor(ay, 32, 64);
    if (half == 0) {
        float2 o;
        o.x = ax * dd + bias[2 * l32];
        o.y = ay * dd + bias[2 * l32 + 1];
        ((float2*)out)[(size_t)node * 32 + l32] = o;
    }
}

extern "C" void kernel_launch(void* const* d_in, const int* in_sizes, int n_in,
                              void* d_out, int out_size, void* d_ws, size_t ws_size,
                              hipStream_t stream) {
    const float* x  = (const float*)d_in[0];
    const int*   ei = (const int*)d_in[1];
    const float* W1 = (const float*)d_in[2];
    const float* b1 = (const float*)d_in[3];
    const float* W2 = (const float*)d_in[4];
    const float* b2 = (const float*)d_in[5];

    const int N = in_sizes[0] / IN_C;               // 50000
    const int E = in_sizes[1] / 2;                  // 800000
    const int NBK  = (N + BK - 1) / BK;             // 391 buckets
    const int NCHK = (E + 2047) / 2048;             // 391 edge chunks
    const int NT1  = (N + 63) / 64;                 // 782 GEMM1 tiles

    char* ws = (char*)d_ws;
    int*            flag    = (int*)(ws + 0);
    int*            bcnt    = (int*)(ws + 64);
    int*            bptr    = (int*)(ws + 2048);
    int*            bfill   = (int*)(ws + 4096);
    int*            row_ptr = (int*)(ws + 8192);
    float*          dinv    = (float*)(ws + 212992);
    int*            col     = (int*)(ws + 413696);
    unsigned short* w1f     = (unsigned short*)(ws + 3620864);
    unsigned short* w2f     = (unsigned short*)(ws + 3653632);
    int2*           ebuf    = (int2*)(ws + 3670016);
    unsigned short* h       = (unsigned short*)(ws + 10070016);  // bf16 [N,128]; reused as h2 [N,64]
    unsigned int*   h1b     = (unsigned int*)(ws + 22870016);    // bf16 [N,128] packed dwords

    // ---- setup (weights + dtype probe + bcnt zero) ----
    k_setup<<<96, 256, 0, stream>>>(W1, W2, ei, w1f, w2f, flag, bcnt, NBK);

    // ---- CSR build ----
    k_bhist<<<NCHK, 256, 0, stream>>>(ei, flag, bcnt, E, NBK);
    k_bscan<<<1, 256, 0, stream>>>(bcnt, bptr, bfill, NBK);
    k_bpart<<<NCHK, 256, 0, stream>>>(ei, flag, bfill, ebuf, E, NBK);

    // ---- fused: bucket-local CSR finalize + GEMM1 ----
    k_blmg1<<<NBK + NT1, 256, 0, stream>>>(ebuf, bptr, row_ptr, dinv, col,
                                           x, w1f, h, E, N, NBK);

    // ---- layer 1 aggregation (+b1, ReLU, bf16) ----
    k_agg128e<<<(N + 3) / 4, 256, 0, stream>>>((const unsigned int*)h, row_ptr, col, dinv, b1, h1b, N);

    // ---- layer 2 ----
    unsigned short* h2 = h;                          // h dead after agg128e
    k_mg2<<<NT1, 256, 0, stream>>>(h1b, w2f, h2, N);
    k_agg64<<<(N + 3) / 4, 256, 0, stream>>>((const unsigned int*)h2, row_ptr, col, dinv, b2, (float*)d_out, N);
}

// Round 9
// 193.078 us; speedup vs baseline: 4.0550x; 1.0730x over previous
//
#include <hip/hip_runtime.h>
#include <hip/hip_bf16.h>

#define IN_C  128
#define HID_C 128
#define OUT_CC 64
#define BK    128           // nodes per bucket (dst >> 7)

using short8  = __attribute__((ext_vector_type(8))) short;
using float4v = __attribute__((ext_vector_type(4))) float;

// fp32 -> bf16 (round-to-nearest-even, finite inputs)
__device__ __forceinline__ unsigned short f2b(float f) {
    unsigned int u = __float_as_uint(f);
    return (unsigned short)((u + 0x7fffu + ((u >> 16) & 1u)) >> 16);
}
__device__ __forceinline__ unsigned int pack2(float a, float b) {
    return (unsigned int)f2b(a) | ((unsigned int)f2b(b) << 16);
}
__device__ __forceinline__ float2 bf2_to_f2(unsigned int v) {
    float2 r;
    r.x = __uint_as_float(v << 16);
    r.y = __uint_as_float(v & 0xffff0000u);
    return r;
}

// ---- ws layout (bytes) ----
// flag      int           @ 0
// bcnt      int[391]      @ 64
// bptr      int[392]      @ 2048
// bfill     int[391]      @ 4096
// row_ptr   int[N+1]      @ 8192
// dinv      float[N]      @ 212992
// col       int[E]        @ 413696
// w1frag    bf16[16384]   @ 3620864
// w2frag    bf16[8192]    @ 3653632
// ebuf      int2[E]       @ 3670016     (ends 10,070,016)
// h (bf16)  [N*128]       @ 10070016    (reused as h2 bf16 [N,64] after agg128e)
// h1b(bf16) [N*128]       @ 22870016    (ends ~35.7 MB)

// ---------------- setup: weight prep + edge dtype probe + bcnt zero ----------------
__global__ __launch_bounds__(256) void k_setup(const float* __restrict__ W1,
                                               const float* __restrict__ W2,
                                               const int* __restrict__ ei,
                                               unsigned short* __restrict__ w1f,
                                               unsigned short* __restrict__ w2f,
                                               int* __restrict__ flag,
                                               int* __restrict__ bcnt, int NBK) {
    int e = blockIdx.x * 256 + threadIdx.x;
    if (e < 16384) {                                  // W1: frag ((nt*4+ks)*64+lane)*8+j
        int j = e & 7, lane = (e >> 3) & 63, ks = (e >> 9) & 3, nt = e >> 11;
        int k = ks * 32 + ((lane >> 4) << 3) + j;
        int n = nt * 16 + (lane & 15);
        w1f[e] = f2b(W1[k * 128 + n]);
    } else if (e < 16384 + 8192) {
        int e2 = e - 16384;
        int j = e2 & 7, lane = (e2 >> 3) & 63, ks = (e2 >> 9) & 3, nt = e2 >> 11;
        int k = ks * 32 + ((lane >> 4) << 3) + j;
        int n = nt * 16 + (lane & 15);
        w2f[e2] = f2b(W2[k * 64 + n]);
    }
    if (blockIdx.x == 0) {
        for (int i = threadIdx.x; i < NBK; i += 256) bcnt[i] = 0;
        if (threadIdx.x == 0) {
            int odd_zero = 1, any_even = 0;
            for (int i = 0; i < 64; ++i) {
                if (ei[2 * i + 1] != 0) odd_zero = 0;
                if (ei[2 * i] != 0) any_even = 1;
            }
            *flag = (odd_zero && any_even) ? 2 : 1;
        }
    }
}

// ---------------- bucket histogram: NBK coarse buckets ----------------
__global__ __launch_bounds__(256) void k_bhist(const int* __restrict__ ei,
                                               const int* __restrict__ flag,
                                               int* __restrict__ bcnt, int E, int NBK) {
    __shared__ int lh[512];
    for (int i = threadIdx.x; i < NBK; i += 256) lh[i] = 0;
    __syncthreads();
    const int st = *flag;
    const int base = blockIdx.x * 2048;
    const int lim = min(base + 2048, E);
    for (int i = base + threadIdx.x; i < lim; i += 256) {
        int d = ei[(size_t)st * ((size_t)E + i)];
        atomicAdd(&lh[d >> 7], 1);
    }
    __syncthreads();
    for (int i = threadIdx.x; i < NBK; i += 256)
        if (lh[i]) atomicAdd(&bcnt[i], lh[i]);
}

// ---------------- scan bucket counts -> bptr, init bfill ----------------
__global__ __launch_bounds__(256) void k_bscan(const int* __restrict__ bcnt,
                                               int* __restrict__ bptr,
                                               int* __restrict__ bfill, int B) {
    __shared__ int part[256];
    const int t = threadIdx.x;
    const int chunk = (B + 255) >> 8;
    int b = t * chunk, e = min(b + chunk, B);
    int s = 0;
    for (int i = b; i < e; ++i) s += bcnt[i];
    part[t] = s;
    __syncthreads();
    for (int off = 1; off < 256; off <<= 1) {
        int v = (t >= off) ? part[t - off] : 0;
        __syncthreads();
        part[t] += v;
        __syncthreads();
    }
    int excl = (t == 0) ? 0 : part[t - 1];
    for (int i = b; i < e; ++i) {
        bptr[i] = excl; bfill[i] = excl;
        excl += bcnt[i];
    }
    if (t == 255) bptr[B] = part[255];
}

// ---------------- partition edges into bucket-grouped (src,dst) pairs ----------------
__global__ __launch_bounds__(256) void k_bpart(const int* __restrict__ ei,
                                               const int* __restrict__ flag,
                                               int* __restrict__ bfill,
                                               int2* __restrict__ ebuf, int E, int NBK) {
    __shared__ int lh[512];
    __shared__ int lbase[512];
    const int t = threadIdx.x;
    for (int i = t; i < NBK; i += 256) lh[i] = 0;
    __syncthreads();
    const int st = *flag;
    const int base = blockIdx.x * 2048;
    int s[8], d[8];
    #pragma unroll
    for (int j = 0; j < 8; ++j) {
        int i = base + j * 256 + t;
        if (i < E) {
            s[j] = ei[(size_t)st * i];
            d[j] = ei[(size_t)st * ((size_t)E + i)];
            atomicAdd(&lh[d[j] >> 7], 1);
        } else d[j] = -1;
    }
    __syncthreads();
    for (int i = t; i < NBK; i += 256) {
        int c = lh[i];
        lbase[i] = c ? atomicAdd(&bfill[i], c) : 0;
        lh[i] = 0;                                   // becomes local rank counter
    }
    __syncthreads();
    #pragma unroll
    for (int j = 0; j < 8; ++j) {
        if (d[j] >= 0) {
            int b = d[j] >> 7;
            int r = atomicAdd(&lh[b], 1);
            ebuf[lbase[b] + r] = make_int2(s[j], d[j]);
        }
    }
}

// ---------------- fused: per-bucket local CSR (blocks < NBK) | MFMA GEMM1 (rest) ----
__global__ __launch_bounds__(256) void k_blmg1(const int2* __restrict__ ebuf,
                                               const int* __restrict__ bptr,
                                               int* __restrict__ row_ptr,
                                               float* __restrict__ dinv,
                                               int* __restrict__ col,
                                               const float* __restrict__ x,
                                               const unsigned short* __restrict__ w1f,
                                               unsigned short* __restrict__ h,
                                               int E, int N, int NBK) {
    __shared__ unsigned short lds[64 * 136];          // 17.4 KB, shared by both paths
    const int t = threadIdx.x;

    if ((int)blockIdx.x < NBK) {
        // ---- per-bucket CSR build ----
        int* cnt = (int*)lds;
        int* sc  = cnt + BK;
        int* off = sc + BK;
        const int n0 = blockIdx.x * BK;
        const int beg = bptr[blockIdx.x], end = bptr[blockIdx.x + 1];
        if (t < BK) cnt[t] = 0;
        __syncthreads();
        for (int i = beg + t; i < end; i += 256)
            atomicAdd(&cnt[ebuf[i].y - n0], 1);
        __syncthreads();
        if (t < BK) sc[t] = cnt[t];
        __syncthreads();
        for (int o = 1; o < BK; o <<= 1) {
            int v = (t < BK && t >= o) ? sc[t - o] : 0;
            __syncthreads();
            if (t < BK) sc[t] += v;
            __syncthreads();
        }
        if (t < BK) {
            off[t] = sc[t] - cnt[t];
            if (n0 + t < N) {
                row_ptr[n0 + t] = beg + off[t];
                dinv[n0 + t] = rsqrtf((float)cnt[t] + 1.0f);
            }
            cnt[t] = 0;
        }
        if ((int)blockIdx.x == NBK - 1 && t == 0) row_ptr[N] = E;
        __syncthreads();
        for (int i = beg + t; i < end; i += 256) {
            int2 e = ebuf[i];
            int dl = e.y - n0;
            int p = beg + off[dl] + atomicAdd(&cnt[dl], 1);
            col[p] = e.x;
        }
        return;
    }

    // ---- MFMA GEMM1 tile ----
    const int row0 = ((int)blockIdx.x - NBK) * 64;
    {
        int r = t >> 2, cc = (t & 3) * 32;
        int grow = row0 + r;
        unsigned int* dst = (unsigned int*)&lds[r * 136 + cc];
        if (grow < N) {
            const float4* src = (const float4*)(x + (size_t)grow * 128 + cc);
            #pragma unroll
            for (int i = 0; i < 8; ++i) {
                float4 v = src[i];
                dst[2 * i]     = pack2(v.x, v.y);
                dst[2 * i + 1] = pack2(v.z, v.w);
            }
        } else {
            #pragma unroll
            for (int i = 0; i < 16; ++i) dst[i] = 0;
        }
    }
    __syncthreads();
    const int w = t >> 6, lane = t & 63;
    const int quad = lane >> 4, m = lane & 15;
    short8 a[4];
    #pragma unroll
    for (int ks = 0; ks < 4; ++ks)
        a[ks] = *(const short8*)&lds[(w * 16 + m) * 136 + ks * 32 + quad * 8];
    float4v acc[8];
    #pragma unroll
    for (int nt = 0; nt < 8; ++nt) acc[nt] = (float4v){0.f, 0.f, 0.f, 0.f};
    const short8* wf = (const short8*)w1f;
    #pragma unroll
    for (int nt = 0; nt < 8; ++nt)
        #pragma unroll
        for (int ks = 0; ks < 4; ++ks)
            acc[nt] = __builtin_amdgcn_mfma_f32_16x16x32_bf16(a[ks], wf[(nt * 4 + ks) * 64 + lane],
                                                              acc[nt], 0, 0, 0);
    #pragma unroll
    for (int nt = 0; nt < 8; ++nt)
        #pragma unroll
        for (int r = 0; r < 4; ++r) {
            int grow = row0 + w * 16 + quad * 4 + r;   // C/D: col=lane&15, row=quad*4+reg
            if (grow < N) h[(size_t)grow * 128 + nt * 16 + m] = f2b(acc[nt][r]);
        }
}

// ---------------- agg layer 1 + bias + ReLU + bf16: one node per 32-lane half ----------
// feat rows = 32 uint2 (128 bf16); 8 outstanding row-gathers per wave (2 nodes x unroll 4)
__global__ __launch_bounds__(256) void k_agg128e(const uint2* __restrict__ feat,
                                                 const int* __restrict__ row_ptr,
                                                 const int* __restrict__ col,
                                                 const float* __restrict__ dinv,
                                                 const float* __restrict__ b1,
                                                 uint2* __restrict__ h1b, int N) {
    const int wave = threadIdx.x >> 6, lane = threadIdx.x & 63;
    const int half = lane >> 5, l32 = lane & 31;
    const int node = blockIdx.x * 8 + wave * 2 + half;
    if (node >= N) return;
    const float dd = dinv[node];
    const int beg = row_ptr[node], end = row_ptr[node + 1];
    uint2 sv = feat[(size_t)node * 32 + l32];               // self-loop
    float2 p0 = bf2_to_f2(sv.x), p1 = bf2_to_f2(sv.y);
    float a0 = p0.x * dd, a1 = p0.y * dd, a2 = p1.x * dd, a3 = p1.y * dd;
    int e = beg;
    for (; e + 4 <= end; e += 4) {
        int s0 = col[e], s1 = col[e + 1], s2 = col[e + 2], s3 = col[e + 3];
        float w0 = dinv[s0], w1 = dinv[s1], w2 = dinv[s2], w3 = dinv[s3];
        uint2 u0 = feat[(size_t)s0 * 32 + l32];
        uint2 u1 = feat[(size_t)s1 * 32 + l32];
        uint2 u2 = feat[(size_t)s2 * 32 + l32];
        uint2 u3 = feat[(size_t)s3 * 32 + l32];
        float2 q;
        q = bf2_to_f2(u0.x); a0 += q.x * w0; a1 += q.y * w0;
        q = bf2_to_f2(u0.y); a2 += q.x * w0; a3 += q.y * w0;
        q = bf2_to_f2(u1.x); a0 += q.x * w1; a1 += q.y * w1;
        q = bf2_to_f2(u1.y); a2 += q.x * w1; a3 += q.y * w1;
        q = bf2_to_f2(u2.x); a0 += q.x * w2; a1 += q.y * w2;
        q = bf2_to_f2(u2.y); a2 += q.x * w2; a3 += q.y * w2;
        q = bf2_to_f2(u3.x); a0 += q.x * w3; a1 += q.y * w3;
        q = bf2_to_f2(u3.y); a2 += q.x * w3; a3 += q.y * w3;
    }
    for (; e < end; ++e) {
        int s = col[e];
        float w = dinv[s];
        uint2 u = feat[(size_t)s * 32 + l32];
        float2 q;
        q = bf2_to_f2(u.x); a0 += q.x * w; a1 += q.y * w;
        q = bf2_to_f2(u.y); a2 += q.x * w; a3 += q.y * w;
    }
    float4 b = ((const float4*)b1)[l32];
    a0 = fmaxf(a0 * dd + b.x, 0.0f);
    a1 = fmaxf(a1 * dd + b.y, 0.0f);
    a2 = fmaxf(a2 * dd + b.z, 0.0f);
    a3 = fmaxf(a3 * dd + b.w, 0.0f);
    h1b[(size_t)node * 32 + l32] = make_uint2(pack2(a0, a1), pack2(a2, a3));
}

// ---------------- MFMA GEMM2: h2[N,64] = h1b(bf16) @ bf16(W2), bf16 store ----------------
__global__ __launch_bounds__(256) void k_mg2(const unsigned int* __restrict__ h1b,
                                             const unsigned short* __restrict__ w2f,
                                             unsigned short* __restrict__ h2, int N) {
    __shared__ unsigned short lds[64 * 136];
    const int t = threadIdx.x;
    const int row0 = blockIdx.x * 64;
    {   // stage: straight bf16 copy (bias+relu already applied)
        int r = t >> 2, cc = (t & 3) * 32;
        int grow = row0 + r;
        uint4* dst = (uint4*)&lds[r * 136 + cc];
        if (grow < N) {
            const uint4* src = (const uint4*)(h1b + (size_t)grow * 64 + (cc >> 1));
            #pragma unroll
            for (int i = 0; i < 4; ++i) dst[i] = src[i];
        } else {
            #pragma unroll
            for (int i = 0; i < 4; ++i) dst[i] = (uint4){0, 0, 0, 0};
        }
    }
    __syncthreads();
    const int w = t >> 6, lane = t & 63;
    const int quad = lane >> 4, m = lane & 15;
    short8 a[4];
    #pragma unroll
    for (int ks = 0; ks < 4; ++ks)
        a[ks] = *(const short8*)&lds[(w * 16 + m) * 136 + ks * 32 + quad * 8];
    float4v acc[4];
    #pragma unroll
    for (int nt = 0; nt < 4; ++nt) acc[nt] = (float4v){0.f, 0.f, 0.f, 0.f};
    const short8* wf = (const short8*)w2f;
    #pragma unroll
    for (int nt = 0; nt < 4; ++nt)
        #pragma unroll
        for (int ks = 0; ks < 4; ++ks)
            acc[nt] = __builtin_amdgcn_mfma_f32_16x16x32_bf16(a[ks], wf[(nt * 4 + ks) * 64 + lane],
                                                              acc[nt], 0, 0, 0);
    #pragma unroll
    for (int nt = 0; nt < 4; ++nt)
        #pragma unroll
        for (int r = 0; r < 4; ++r) {
            int grow = row0 + w * 16 + quad * 4 + r;
            if (grow < N) h2[(size_t)grow * 64 + nt * 16 + m] = f2b(acc[nt][r]);
        }
}

// ---------------- agg layer 2: one node per 32-lane half, +b2, out fp32 ----------------
__global__ __launch_bounds__(256) void k_agg64(const unsigned int* __restrict__ feat,
                                               const int* __restrict__ row_ptr,
                                               const int* __restrict__ col,
                                               const float* __restrict__ dinv,
                                               const float* __restrict__ bias,
                                               float* __restrict__ out, int N) {
    const int wave = threadIdx.x >> 6, lane = threadIdx.x & 63;
    const int half = lane >> 5, l32 = lane & 31;
    const int node = blockIdx.x * 8 + wave * 2 + half;
    if (node >= N) return;
    const float dd = dinv[node];
    const int beg = row_ptr[node], end = row_ptr[node + 1];
    float2 sv = bf2_to_f2(feat[(size_t)node * 32 + l32]);   // self-loop
    float ax = sv.x * dd, ay = sv.y * dd;
    int e = beg;
    for (; e + 4 <= end; e += 4) {
        int s0 = col[e], s1 = col[e + 1], s2 = col[e + 2], s3 = col[e + 3];
        float w0 = dinv[s0], w1 = dinv[s1], w2 = dinv[s2], w3 = dinv[s3];
        float2 v0 = bf2_to_f2(feat[(size_t)s0 * 32 + l32]);
        float2 v1 = bf2_to_f2(feat[(size_t)s1 * 32 + l32]);
        float2 v2 = bf2_to_f2(feat[(size_t)s2 * 32 + l32]);
        float2 v3 = bf2_to_f2(feat[(size_t)s3 * 32 + l32]);
        ax += v0.x * w0 + v1.x * w1 + v2.x * w2 + v3.x * w3;
        ay += v0.y * w0 + v1.y * w1 + v2.y * w2 + v3.y * w3;
    }
    for (; e < end; ++e) {
        int s = col[e];
        float w = dinv[s];
        float2 v = bf2_to_f2(feat[(size_t)s * 32 + l32]);
        ax += v.x * w;
        ay += v.y * w;
    }
    float2 b = ((const float2*)bias)[l32];
    float2 o;
    o.x = ax * dd + b.x;
    o.y = ay * dd + b.y;
    ((float2*)out)[(size_t)node * 32 + l32] = o;
}

extern "C" void kernel_launch(void* const* d_in, const int* in_sizes, int n_in,
                              void* d_out, int out_size, void* d_ws, size_t ws_size,
                              hipStream_t stream) {
    const float* x  = (const float*)d_in[0];
    const int*   ei = (const int*)d_in[1];
    const float* W1 = (const float*)d_in[2];
    const float* b1 = (const float*)d_in[3];
    const float* W2 = (const float*)d_in[4];
    const float* b2 = (const float*)d_in[5];

    const int N = in_sizes[0] / IN_C;               // 50000
    const int E = in_sizes[1] / 2;                  // 800000
    const int NBK  = (N + BK - 1) / BK;             // 391 buckets
    const int NCHK = (E + 2047) / 2048;             // 391 edge chunks
    const int NT1  = (N + 63) / 64;                 // 782 GEMM1 tiles

    char* ws = (char*)d_ws;
    int*            flag    = (int*)(ws + 0);
    int*            bcnt    = (int*)(ws + 64);
    int*            bptr    = (int*)(ws + 2048);
    int*            bfill   = (int*)(ws + 4096);
    int*            row_ptr = (int*)(ws + 8192);
    float*          dinv    = (float*)(ws + 212992);
    int*            col     = (int*)(ws + 413696);
    unsigned short* w1f     = (unsigned short*)(ws + 3620864);
    unsigned short* w2f     = (unsigned short*)(ws + 3653632);
    int2*           ebuf    = (int2*)(ws + 3670016);
    unsigned short* h       = (unsigned short*)(ws + 10070016);  // bf16 [N,128]; reused as h2 [N,64]
    uint2*          h1b     = (uint2*)(ws + 22870016);           // bf16 [N,128] packed

    // ---- setup (weights + dtype probe + bcnt zero) ----
    k_setup<<<96, 256, 0, stream>>>(W1, W2, ei, w1f, w2f, flag, bcnt, NBK);

    // ---- CSR build ----
    k_bhist<<<NCHK, 256, 0, stream>>>(ei, flag, bcnt, E, NBK);
    k_bscan<<<1, 256, 0, stream>>>(bcnt, bptr, bfill, NBK);
    k_bpart<<<NCHK, 256, 0, stream>>>(ei, flag, bfill, ebuf, E, NBK);

    // ---- fused: bucket-local CSR finalize + GEMM1 ----
    k_blmg1<<<NBK + NT1, 256, 0, stream>>>(ebuf, bptr, row_ptr, dinv, col,
                                           x, w1f, h, E, N, NBK);

    // ---- layer 1 aggregation (+b1, ReLU, bf16) ----
    k_agg128e<<<(N + 7) / 8, 256, 0, stream>>>((const uint2*)h, row_ptr, col, dinv, b1, h1b, N);

    // ---- layer 2 ----
    unsigned short* h2 = h;                          // h dead after agg128e
    k_mg2<<<NT1, 256, 0, stream>>>((const unsigned int*)h1b, w2f, h2, N);
    k_agg64<<<(N + 7) / 8, 256, 0, stream>>>((const unsigned int*)h2, row_ptr, col, dinv, b2, (float*)d_out, N);
}

// Round 10
// 185.776 us; speedup vs baseline: 4.2144x; 1.0393x over previous
//
#include <hip/hip_runtime.h>
#include <hip/hip_bf16.h>

#define IN_C  128
#define HID_C 128
#define OUT_CC 64
#define BK    128           // nodes per bucket (dst >> 7)

using short8  = __attribute__((ext_vector_type(8))) short;
using float4v = __attribute__((ext_vector_type(4))) float;

// fp32 -> bf16 (round-to-nearest-even, finite inputs)
__device__ __forceinline__ unsigned short f2b(float f) {
    unsigned int u = __float_as_uint(f);
    return (unsigned short)((u + 0x7fffu + ((u >> 16) & 1u)) >> 16);
}
__device__ __forceinline__ unsigned int pack2(float a, float b) {
    return (unsigned int)f2b(a) | ((unsigned int)f2b(b) << 16);
}
__device__ __forceinline__ float2 bf2_to_f2(unsigned int v) {
    float2 r;
    r.x = __uint_as_float(v << 16);
    r.y = __uint_as_float(v & 0xffff0000u);
    return r;
}

// ---- ws layout (bytes) ----
// flag      int           @ 0
// bcnt      int[391]      @ 64
// bptr      int[392]      @ 2048
// bfill     int[391]      @ 4096
// row_ptr   int[N+1]      @ 8192
// dinv      float[N]      @ 212992
// col       int[E]        @ 413696
// w1frag    bf16[16384]   @ 3620864
// w2frag    bf16[8192]    @ 3653632
// ebuf      int[E] packed @ 3670016     (src | dlocal<<20; ends 6,870,016)
// h (bf16)  [N*128]       @ 10070016    (reused as h2 bf16 [N,64] after agg128e)
// h1b(bf16) [N*128]       @ 22870016    (ends ~35.7 MB)

// ---------------- setup: weight prep + edge dtype probe + bcnt zero ----------------
__global__ __launch_bounds__(256) void k_setup(const float* __restrict__ W1,
                                               const float* __restrict__ W2,
                                               const int* __restrict__ ei,
                                               unsigned short* __restrict__ w1f,
                                               unsigned short* __restrict__ w2f,
                                               int* __restrict__ flag,
                                               int* __restrict__ bcnt, int NBK) {
    int e = blockIdx.x * 256 + threadIdx.x;
    if (e < 16384) {                                  // W1: frag ((nt*4+ks)*64+lane)*8+j
        int j = e & 7, lane = (e >> 3) & 63, ks = (e >> 9) & 3, nt = e >> 11;
        int k = ks * 32 + ((lane >> 4) << 3) + j;
        int n = nt * 16 + (lane & 15);
        w1f[e] = f2b(W1[k * 128 + n]);
    } else if (e < 16384 + 8192) {
        int e2 = e - 16384;
        int j = e2 & 7, lane = (e2 >> 3) & 63, ks = (e2 >> 9) & 3, nt = e2 >> 11;
        int k = ks * 32 + ((lane >> 4) << 3) + j;
        int n = nt * 16 + (lane & 15);
        w2f[e2] = f2b(W2[k * 64 + n]);
    }
    if (blockIdx.x == 0) {
        for (int i = threadIdx.x; i < NBK; i += 256) bcnt[i] = 0;
        if (threadIdx.x == 0) {
            int odd_zero = 1, any_even = 0;
            for (int i = 0; i < 64; ++i) {
                if (ei[2 * i + 1] != 0) odd_zero = 0;
                if (ei[2 * i] != 0) any_even = 1;
            }
            *flag = (odd_zero && any_even) ? 2 : 1;
        }
    }
}

// ---------------- bucket histogram: NBK coarse buckets ----------------
__global__ __launch_bounds__(256) void k_bhist(const int* __restrict__ ei,
                                               const int* __restrict__ flag,
                                               int* __restrict__ bcnt, int E, int NBK) {
    __shared__ int lh[512];
    for (int i = threadIdx.x; i < NBK; i += 256) lh[i] = 0;
    __syncthreads();
    const int st = *flag;
    const int base = blockIdx.x * 2048;
    const int lim = min(base + 2048, E);
    for (int i = base + threadIdx.x; i < lim; i += 256) {
        int d = ei[(size_t)st * ((size_t)E + i)];
        atomicAdd(&lh[d >> 7], 1);
    }
    __syncthreads();
    for (int i = threadIdx.x; i < NBK; i += 256)
        if (lh[i]) atomicAdd(&bcnt[i], lh[i]);
}

// ---------------- scan bucket counts -> bptr, init bfill ----------------
__global__ __launch_bounds__(256) void k_bscan(const int* __restrict__ bcnt,
                                               int* __restrict__ bptr,
                                               int* __restrict__ bfill, int B) {
    __shared__ int part[256];
    const int t = threadIdx.x;
    const int chunk = (B + 255) >> 8;
    int b = t * chunk, e = min(b + chunk, B);
    int s = 0;
    for (int i = b; i < e; ++i) s += bcnt[i];
    part[t] = s;
    __syncthreads();
    for (int off = 1; off < 256; off <<= 1) {
        int v = (t >= off) ? part[t - off] : 0;
        __syncthreads();
        part[t] += v;
        __syncthreads();
    }
    int excl = (t == 0) ? 0 : part[t - 1];
    for (int i = b; i < e; ++i) {
        bptr[i] = excl; bfill[i] = excl;
        excl += bcnt[i];
    }
    if (t == 255) bptr[B] = part[255];
}

// ---------------- partition edges into bucket-grouped packed ints ----------------
// packed = src | (dst & 127) << 20   (src < 2^20, BK=128)
__global__ __launch_bounds__(256) void k_bpart(const int* __restrict__ ei,
                                               const int* __restrict__ flag,
                                               int* __restrict__ bfill,
                                               int* __restrict__ ebuf, int E, int NBK) {
    __shared__ int lh[512];
    __shared__ int lbase[512];
    const int t = threadIdx.x;
    for (int i = t; i < NBK; i += 256) lh[i] = 0;
    __syncthreads();
    const int st = *flag;
    const int base = blockIdx.x * 2048;
    int s[8], d[8];
    #pragma unroll
    for (int j = 0; j < 8; ++j) {
        int i = base + j * 256 + t;
        if (i < E) {
            s[j] = ei[(size_t)st * i];
            d[j] = ei[(size_t)st * ((size_t)E + i)];
            atomicAdd(&lh[d[j] >> 7], 1);
        } else d[j] = -1;
    }
    __syncthreads();
    for (int i = t; i < NBK; i += 256) {
        int c = lh[i];
        lbase[i] = c ? atomicAdd(&bfill[i], c) : 0;
        lh[i] = 0;                                   // becomes local rank counter
    }
    __syncthreads();
    #pragma unroll
    for (int j = 0; j < 8; ++j) {
        if (d[j] >= 0) {
            int b = d[j] >> 7;
            int r = atomicAdd(&lh[b], 1);
            ebuf[lbase[b] + r] = s[j] | ((d[j] & (BK - 1)) << 20);
        }
    }
}

// ---------------- fused: per-bucket local CSR (blocks < NBK) | MFMA GEMM1 (rest) ----
__global__ __launch_bounds__(256) void k_blmg1(const int* __restrict__ ebuf,
                                               const int* __restrict__ bptr,
                                               int* __restrict__ row_ptr,
                                               float* __restrict__ dinv,
                                               int* __restrict__ col,
                                               const float* __restrict__ x,
                                               const unsigned short* __restrict__ w1f,
                                               unsigned short* __restrict__ h,
                                               int E, int N, int NBK) {
    __shared__ unsigned short lds[64 * 136];          // 17.4 KB, shared by both paths
    const int t = threadIdx.x;

    if ((int)blockIdx.x < NBK) {
        // ---- per-bucket CSR build ----
        int* cnt = (int*)lds;
        int* sc  = cnt + BK;
        int* off = sc + BK;
        const int n0 = blockIdx.x * BK;
        const int beg = bptr[blockIdx.x], end = bptr[blockIdx.x + 1];
        if (t < BK) cnt[t] = 0;
        __syncthreads();
        for (int i = beg + t; i < end; i += 256)
            atomicAdd(&cnt[ebuf[i] >> 20], 1);
        __syncthreads();
        if (t < BK) sc[t] = cnt[t];
        __syncthreads();
        for (int o = 1; o < BK; o <<= 1) {
            int v = (t < BK && t >= o) ? sc[t - o] : 0;
            __syncthreads();
            if (t < BK) sc[t] += v;
            __syncthreads();
        }
        if (t < BK) {
            off[t] = sc[t] - cnt[t];
            if (n0 + t < N) {
                row_ptr[n0 + t] = beg + off[t];
                dinv[n0 + t] = rsqrtf((float)cnt[t] + 1.0f);
            }
            cnt[t] = 0;
        }
        if ((int)blockIdx.x == NBK - 1 && t == 0) row_ptr[N] = E;
        __syncthreads();
        for (int i = beg + t; i < end; i += 256) {
            int e = ebuf[i];
            int dl = e >> 20;
            int p = beg + off[dl] + atomicAdd(&cnt[dl], 1);
            col[p] = e & 0xFFFFF;
        }
        return;
    }

    // ---- MFMA GEMM1 tile ----
    const int row0 = ((int)blockIdx.x - NBK) * 64;
    {
        int r = t >> 2, cc = (t & 3) * 32;
        int grow = row0 + r;
        unsigned int* dst = (unsigned int*)&lds[r * 136 + cc];
        if (grow < N) {
            const float4* src = (const float4*)(x + (size_t)grow * 128 + cc);
            #pragma unroll
            for (int i = 0; i < 8; ++i) {
                float4 v = src[i];
                dst[2 * i]     = pack2(v.x, v.y);
                dst[2 * i + 1] = pack2(v.z, v.w);
            }
        } else {
            #pragma unroll
            for (int i = 0; i < 16; ++i) dst[i] = 0;
        }
    }
    __syncthreads();
    const int w = t >> 6, lane = t & 63;
    const int quad = lane >> 4, m = lane & 15;
    short8 a[4];
    #pragma unroll
    for (int ks = 0; ks < 4; ++ks)
        a[ks] = *(const short8*)&lds[(w * 16 + m) * 136 + ks * 32 + quad * 8];
    float4v acc[8];
    #pragma unroll
    for (int nt = 0; nt < 8; ++nt) acc[nt] = (float4v){0.f, 0.f, 0.f, 0.f};
    const short8* wf = (const short8*)w1f;
    #pragma unroll
    for (int nt = 0; nt < 8; ++nt)
        #pragma unroll
        for (int ks = 0; ks < 4; ++ks)
            acc[nt] = __builtin_amdgcn_mfma_f32_16x16x32_bf16(a[ks], wf[(nt * 4 + ks) * 64 + lane],
                                                              acc[nt], 0, 0, 0);
    #pragma unroll
    for (int nt = 0; nt < 8; ++nt)
        #pragma unroll
        for (int r = 0; r < 4; ++r) {
            int grow = row0 + w * 16 + quad * 4 + r;   // C/D: col=lane&15, row=quad*4+reg
            if (grow < N) h[(size_t)grow * 128 + nt * 16 + m] = f2b(acc[nt][r]);
        }
}

// ---------------- agg layer 1 + bias + ReLU + bf16: one node per 16 lanes ----------
// feat rows = 16 uint4 (128 bf16); 16 outstanding row-gathers per wave (4 nodes x unroll 4)
__global__ __launch_bounds__(256) void k_agg128e(const uint4* __restrict__ feat,
                                                 const int* __restrict__ row_ptr,
                                                 const int* __restrict__ col,
                                                 const float* __restrict__ dinv,
                                                 const float* __restrict__ b1,
                                                 uint4* __restrict__ h1b, int N) {
    const int grp = threadIdx.x >> 4;                  // 16 groups per block
    const int l16 = threadIdx.x & 15;
    const int node = blockIdx.x * 16 + grp;
    if (node >= N) return;
    const float dd = dinv[node];
    const int beg = row_ptr[node], end = row_ptr[node + 1];
    float a0, a1, a2, a3, a4, a5, a6, a7;
    {
        uint4 sv = feat[(size_t)node * 16 + l16];      // self-loop
        float2 q;
        q = bf2_to_f2(sv.x); a0 = q.x * dd; a1 = q.y * dd;
        q = bf2_to_f2(sv.y); a2 = q.x * dd; a3 = q.y * dd;
        q = bf2_to_f2(sv.z); a4 = q.x * dd; a5 = q.y * dd;
        q = bf2_to_f2(sv.w); a6 = q.x * dd; a7 = q.y * dd;
    }
    int e = beg;
    for (; e + 4 <= end; e += 4) {
        int s0 = col[e], s1 = col[e + 1], s2 = col[e + 2], s3 = col[e + 3];
        float w0 = dinv[s0], w1 = dinv[s1], w2 = dinv[s2], w3 = dinv[s3];
        uint4 u0 = feat[(size_t)s0 * 16 + l16];
        uint4 u1 = feat[(size_t)s1 * 16 + l16];
        uint4 u2 = feat[(size_t)s2 * 16 + l16];
        uint4 u3 = feat[(size_t)s3 * 16 + l16];
        float2 q;
        q = bf2_to_f2(u0.x); a0 += q.x * w0; a1 += q.y * w0;
        q = bf2_to_f2(u0.y); a2 += q.x * w0; a3 += q.y * w0;
        q = bf2_to_f2(u0.z); a4 += q.x * w0; a5 += q.y * w0;
        q = bf2_to_f2(u0.w); a6 += q.x * w0; a7 += q.y * w0;
        q = bf2_to_f2(u1.x); a0 += q.x * w1; a1 += q.y * w1;
        q = bf2_to_f2(u1.y); a2 += q.x * w1; a3 += q.y * w1;
        q = bf2_to_f2(u1.z); a4 += q.x * w1; a5 += q.y * w1;
        q = bf2_to_f2(u1.w); a6 += q.x * w1; a7 += q.y * w1;
        q = bf2_to_f2(u2.x); a0 += q.x * w2; a1 += q.y * w2;
        q = bf2_to_f2(u2.y); a2 += q.x * w2; a3 += q.y * w2;
        q = bf2_to_f2(u2.z); a4 += q.x * w2; a5 += q.y * w2;
        q = bf2_to_f2(u2.w); a6 += q.x * w2; a7 += q.y * w2;
        q = bf2_to_f2(u3.x); a0 += q.x * w3; a1 += q.y * w3;
        q = bf2_to_f2(u3.y); a2 += q.x * w3; a3 += q.y * w3;
        q = bf2_to_f2(u3.z); a4 += q.x * w3; a5 += q.y * w3;
        q = bf2_to_f2(u3.w); a6 += q.x * w3; a7 += q.y * w3;
    }
    for (; e < end; ++e) {
        int s = col[e];
        float w = dinv[s];
        uint4 u = feat[(size_t)s * 16 + l16];
        float2 q;
        q = bf2_to_f2(u.x); a0 += q.x * w; a1 += q.y * w;
        q = bf2_to_f2(u.y); a2 += q.x * w; a3 += q.y * w;
        q = bf2_to_f2(u.z); a4 += q.x * w; a5 += q.y * w;
        q = bf2_to_f2(u.w); a6 += q.x * w; a7 += q.y * w;
    }
    float4 ba = ((const float4*)b1)[2 * l16];
    float4 bb = ((const float4*)b1)[2 * l16 + 1];
    a0 = fmaxf(a0 * dd + ba.x, 0.0f);
    a1 = fmaxf(a1 * dd + ba.y, 0.0f);
    a2 = fmaxf(a2 * dd + ba.z, 0.0f);
    a3 = fmaxf(a3 * dd + ba.w, 0.0f);
    a4 = fmaxf(a4 * dd + bb.x, 0.0f);
    a5 = fmaxf(a5 * dd + bb.y, 0.0f);
    a6 = fmaxf(a6 * dd + bb.z, 0.0f);
    a7 = fmaxf(a7 * dd + bb.w, 0.0f);
    uint4 o;
    o.x = pack2(a0, a1);
    o.y = pack2(a2, a3);
    o.z = pack2(a4, a5);
    o.w = pack2(a6, a7);
    h1b[(size_t)node * 16 + l16] = o;
}

// ---------------- MFMA GEMM2: h2[N,64] = h1b(bf16) @ bf16(W2), bf16 store ----------------
__global__ __launch_bounds__(256) void k_mg2(const unsigned int* __restrict__ h1b,
                                             const unsigned short* __restrict__ w2f,
                                             unsigned short* __restrict__ h2, int N) {
    __shared__ unsigned short lds[64 * 136];
    const int t = threadIdx.x;
    const int row0 = blockIdx.x * 64;
    {   // stage: straight bf16 copy (bias+relu already applied)
        int r = t >> 2, cc = (t & 3) * 32;
        int grow = row0 + r;
        uint4* dst = (uint4*)&lds[r * 136 + cc];
        if (grow < N) {
            const uint4* src = (const uint4*)(h1b + (size_t)grow * 64 + (cc >> 1));
            #pragma unroll
            for (int i = 0; i < 4; ++i) dst[i] = src[i];
        } else {
            #pragma unroll
            for (int i = 0; i < 4; ++i) dst[i] = (uint4){0, 0, 0, 0};
        }
    }
    __syncthreads();
    const int w = t >> 6, lane = t & 63;
    const int quad = lane >> 4, m = lane & 15;
    short8 a[4];
    #pragma unroll
    for (int ks = 0; ks < 4; ++ks)
        a[ks] = *(const short8*)&lds[(w * 16 + m) * 136 + ks * 32 + quad * 8];
    float4v acc[4];
    #pragma unroll
    for (int nt = 0; nt < 4; ++nt) acc[nt] = (float4v){0.f, 0.f, 0.f, 0.f};
    const short8* wf = (const short8*)w2f;
    #pragma unroll
    for (int nt = 0; nt < 4; ++nt)
        #pragma unroll
        for (int ks = 0; ks < 4; ++ks)
            acc[nt] = __builtin_amdgcn_mfma_f32_16x16x32_bf16(a[ks], wf[(nt * 4 + ks) * 64 + lane],
                                                              acc[nt], 0, 0, 0);
    #pragma unroll
    for (int nt = 0; nt < 4; ++nt)
        #pragma unroll
        for (int r = 0; r < 4; ++r) {
            int grow = row0 + w * 16 + quad * 4 + r;
            if (grow < N) h2[(size_t)grow * 64 + nt * 16 + m] = f2b(acc[nt][r]);
        }
}

// ---------------- agg layer 2: one node per 16 lanes, +b2, out fp32 ----------------
// feat rows = 16 uint2 (64 bf16); 16 outstanding row-gathers per wave
__global__ __launch_bounds__(256) void k_agg64(const uint2* __restrict__ feat,
                                               const int* __restrict__ row_ptr,
                                               const int* __restrict__ col,
                                               const float* __restrict__ dinv,
                                               const float* __restrict__ bias,
                                               float* __restrict__ out, int N) {
    const int grp = threadIdx.x >> 4;
    const int l16 = threadIdx.x & 15;
    const int node = blockIdx.x * 16 + grp;
    if (node >= N) return;
    const float dd = dinv[node];
    const int beg = row_ptr[node], end = row_ptr[node + 1];
    float a0, a1, a2, a3;
    {
        uint2 sv = feat[(size_t)node * 16 + l16];      // self-loop
        float2 q;
        q = bf2_to_f2(sv.x); a0 = q.x * dd; a1 = q.y * dd;
        q = bf2_to_f2(sv.y); a2 = q.x * dd; a3 = q.y * dd;
    }
    int e = beg;
    for (; e + 4 <= end; e += 4) {
        int s0 = col[e], s1 = col[e + 1], s2 = col[e + 2], s3 = col[e + 3];
        float w0 = dinv[s0], w1 = dinv[s1], w2 = dinv[s2], w3 = dinv[s3];
        uint2 u0 = feat[(size_t)s0 * 16 + l16];
        uint2 u1 = feat[(size_t)s1 * 16 + l16];
        uint2 u2 = feat[(size_t)s2 * 16 + l16];
        uint2 u3 = feat[(size_t)s3 * 16 + l16];
        float2 q;
        q = bf2_to_f2(u0.x); a0 += q.x * w0; a1 += q.y * w0;
        q = bf2_to_f2(u0.y); a2 += q.x * w0; a3 += q.y * w0;
        q = bf2_to_f2(u1.x); a0 += q.x * w1; a1 += q.y * w1;
        q = bf2_to_f2(u1.y); a2 += q.x * w1; a3 += q.y * w1;
        q = bf2_to_f2(u2.x); a0 += q.x * w2; a1 += q.y * w2;
        q = bf2_to_f2(u2.y); a2 += q.x * w2; a3 += q.y * w2;
        q = bf2_to_f2(u3.x); a0 += q.x * w3; a1 += q.y * w3;
        q = bf2_to_f2(u3.y); a2 += q.x * w3; a3 += q.y * w3;
    }
    for (; e < end; ++e) {
        int s = col[e];
        float w = dinv[s];
        uint2 u = feat[(size_t)s * 16 + l16];
        float2 q;
        q = bf2_to_f2(u.x); a0 += q.x * w; a1 += q.y * w;
        q = bf2_to_f2(u.y); a2 += q.x * w; a3 += q.y * w;
    }
    float4 b = ((const float4*)bias)[l16];
    float4 o;
    o.x = a0 * dd + b.x;
    o.y = a1 * dd + b.y;
    o.z = a2 * dd + b.z;
    o.w = a3 * dd + b.w;
    ((float4*)out)[(size_t)node * 16 + l16] = o;
}

extern "C" void kernel_launch(void* const* d_in, const int* in_sizes, int n_in,
                              void* d_out, int out_size, void* d_ws, size_t ws_size,
                              hipStream_t stream) {
    const float* x  = (const float*)d_in[0];
    const int*   ei = (const int*)d_in[1];
    const float* W1 = (const float*)d_in[2];
    const float* b1 = (const float*)d_in[3];
    const float* W2 = (const float*)d_in[4];
    const float* b2 = (const float*)d_in[5];

    const int N = in_sizes[0] / IN_C;               // 50000
    const int E = in_sizes[1] / 2;                  // 800000
    const int NBK  = (N + BK - 1) / BK;             // 391 buckets
    const int NCHK = (E + 2047) / 2048;             // 391 edge chunks
    const int NT1  = (N + 63) / 64;                 // 782 GEMM1 tiles

    char* ws = (char*)d_ws;
    int*            flag    = (int*)(ws + 0);
    int*            bcnt    = (int*)(ws + 64);
    int*            bptr    = (int*)(ws + 2048);
    int*            bfill   = (int*)(ws + 4096);
    int*            row_ptr = (int*)(ws + 8192);
    float*          dinv    = (float*)(ws + 212992);
    int*            col     = (int*)(ws + 413696);
    unsigned short* w1f     = (unsigned short*)(ws + 3620864);
    unsigned short* w2f     = (unsigned short*)(ws + 3653632);
    int*            ebuf    = (int*)(ws + 3670016);              // packed src|dlocal<<20
    unsigned short* h       = (unsigned short*)(ws + 10070016);  // bf16 [N,128]; reused as h2 [N,64]
    uint4*          h1b     = (uint4*)(ws + 22870016);           // bf16 [N,128] packed

    // ---- setup (weights + dtype probe + bcnt zero) ----
    k_setup<<<96, 256, 0, stream>>>(W1, W2, ei, w1f, w2f, flag, bcnt, NBK);

    // ---- CSR build ----
    k_bhist<<<NCHK, 256, 0, stream>>>(ei, flag, bcnt, E, NBK);
    k_bscan<<<1, 256, 0, stream>>>(bcnt, bptr, bfill, NBK);
    k_bpart<<<NCHK, 256, 0, stream>>>(ei, flag, bfill, ebuf, E, NBK);

    // ---- fused: bucket-local CSR finalize + GEMM1 ----
    k_blmg1<<<NBK + NT1, 256, 0, stream>>>(ebuf, bptr, row_ptr, dinv, col,
                                           x, w1f, h, E, N, NBK);

    // ---- layer 1 aggregation (+b1, ReLU, bf16) ----
    k_agg128e<<<(N + 15) / 16, 256, 0, stream>>>((const uint4*)h, row_ptr, col, dinv, b1, h1b, N);

    // ---- layer 2 ----
    unsigned short* h2 = h;                          // h dead after agg128e
    k_mg2<<<NT1, 256, 0, stream>>>((const unsigned int*)h1b, w2f, h2, N);
    k_agg64<<<(N + 15) / 16, 256, 0, stream>>>((const uint2*)h2, row_ptr, col, dinv, b2, (float*)d_out, N);
}

// Round 11
// 172.368 us; speedup vs baseline: 4.5422x; 1.0778x over previous
//
#include <hip/hip_runtime.h>
#include <hip/hip_bf16.h>

#define IN_C  128
#define HID_C 128
#define OUT_CC 64
#define BK    128           // nodes per bucket (dst >> 7)
#define CAPLG 12            // bucket capacity 4096 edges (mean 2046, >40 sigma)

using short8  = __attribute__((ext_vector_type(8))) short;
using float4v = __attribute__((ext_vector_type(4))) float;

// fp32 -> bf16 (round-to-nearest-even, finite inputs)
__device__ __forceinline__ unsigned short f2b(float f) {
    unsigned int u = __float_as_uint(f);
    return (unsigned short)((u + 0x7fffu + ((u >> 16) & 1u)) >> 16);
}
__device__ __forceinline__ unsigned int pack2(float a, float b) {
    return (unsigned int)f2b(a) | ((unsigned int)f2b(b) << 16);
}
__device__ __forceinline__ float2 bf2_to_f2(unsigned int v) {
    float2 r;
    r.x = __uint_as_float(v << 16);
    r.y = __uint_as_float(v & 0xffff0000u);
    return r;
}

// ---- ws layout (bytes) ----
// flag      int            @ 0
// bfill     int[391]       @ 64
// begend    int2[N]        @ 4096       (ends 404,096)
// dinv      float[N]       @ 404480     (ends 604,480)
// w1frag    bf16[16384]    @ 604672
// w2frag    bf16[8192]     @ 637440
// ebuf      int[391*4096]  @ 655360     (packed src|dlocal<<20; ends 7,061,504)
// col       int[391*4096]  @ 7061504    (ends 13,467,648)
// h (bf16)  [N*128]        @ 13467904   (reused as h2 bf16 [N,64])
// h1b(bf16) [N*128]        @ 26267904   (ends ~39.1 MB)

// ---------------- setup: weight prep + edge dtype probe + bfill zero ----------------
__global__ __launch_bounds__(256) void k_setup(const float* __restrict__ W1,
                                               const float* __restrict__ W2,
                                               const int* __restrict__ ei,
                                               unsigned short* __restrict__ w1f,
                                               unsigned short* __restrict__ w2f,
                                               int* __restrict__ flag,
                                               int* __restrict__ bfill, int NBK) {
    int e = blockIdx.x * 256 + threadIdx.x;
    if (e < 16384) {                                  // W1: frag ((nt*4+ks)*64+lane)*8+j
        int j = e & 7, lane = (e >> 3) & 63, ks = (e >> 9) & 3, nt = e >> 11;
        int k = ks * 32 + ((lane >> 4) << 3) + j;
        int n = nt * 16 + (lane & 15);
        w1f[e] = f2b(W1[k * 128 + n]);
    } else if (e < 16384 + 8192) {
        int e2 = e - 16384;
        int j = e2 & 7, lane = (e2 >> 3) & 63, ks = (e2 >> 9) & 3, nt = e2 >> 11;
        int k = ks * 32 + ((lane >> 4) << 3) + j;
        int n = nt * 16 + (lane & 15);
        w2f[e2] = f2b(W2[k * 64 + n]);
    }
    if (blockIdx.x == 0) {
        for (int i = threadIdx.x; i < NBK; i += 256) bfill[i] = 0;
        if (threadIdx.x == 0) {
            int odd_zero = 1, any_even = 0;
            for (int i = 0; i < 64; ++i) {
                if (ei[2 * i + 1] != 0) odd_zero = 0;
                if (ei[2 * i] != 0) any_even = 1;
            }
            *flag = (odd_zero && any_even) ? 2 : 1;
        }
    }
}

// ---------------- partition edges into fixed-capacity bucket regions ----------------
// ebuf[b<<CAPLG + rank] = src | (dst & 127) << 20
__global__ __launch_bounds__(256) void k_bpart(const int* __restrict__ ei,
                                               const int* __restrict__ flag,
                                               int* __restrict__ bfill,
                                               int* __restrict__ ebuf, int E, int NBK) {
    __shared__ int lh[512];
    __shared__ int lbase[512];
    const int t = threadIdx.x;
    for (int i = t; i < NBK; i += 256) lh[i] = 0;
    __syncthreads();
    const int st = *flag;
    const int base = blockIdx.x * 2048;
    int s[8], d[8];
    #pragma unroll
    for (int j = 0; j < 8; ++j) {
        int i = base + j * 256 + t;
        if (i < E) {
            s[j] = ei[(size_t)st * i];
            d[j] = ei[(size_t)st * ((size_t)E + i)];
            atomicAdd(&lh[d[j] >> 7], 1);
        } else d[j] = -1;
    }
    __syncthreads();
    for (int i = t; i < NBK; i += 256) {
        int c = lh[i];
        lbase[i] = c ? atomicAdd(&bfill[i], c) : 0;
        lh[i] = 0;                                   // becomes local rank counter
    }
    __syncthreads();
    #pragma unroll
    for (int j = 0; j < 8; ++j) {
        if (d[j] >= 0) {
            int b = d[j] >> 7;
            int r = lbase[b] + atomicAdd(&lh[b], 1);
            if (r < (1 << CAPLG))                    // statistical safety clamp
                ebuf[(b << CAPLG) + r] = s[j] | ((d[j] & (BK - 1)) << 20);
        }
    }
}

// ---------------- fused: per-bucket local CSR (blocks < NBK) | MFMA GEMM1 (rest) ----
__global__ __launch_bounds__(256) void k_blmg1(const int* __restrict__ ebuf,
                                               const int* __restrict__ bfill,
                                               int2* __restrict__ begend,
                                               float* __restrict__ dinv,
                                               int* __restrict__ col,
                                               const float* __restrict__ x,
                                               const unsigned short* __restrict__ w1f,
                                               unsigned short* __restrict__ h,
                                               int N, int NBK) {
    __shared__ unsigned short lds[64 * 136];          // 17.4 KB, shared by both paths
    const int t = threadIdx.x;

    if ((int)blockIdx.x < NBK) {
        // ---- per-bucket CSR build ----
        int* cnt = (int*)lds;
        int* sc  = cnt + BK;
        int* off = sc + BK;
        const int n0 = blockIdx.x * BK;
        const int beg = (int)blockIdx.x << CAPLG;
        const int ecnt = min(bfill[blockIdx.x], 1 << CAPLG);
        if (t < BK) cnt[t] = 0;
        __syncthreads();
        for (int i = t; i < ecnt; i += 256)
            atomicAdd(&cnt[ebuf[beg + i] >> 20], 1);
        __syncthreads();
        if (t < BK) sc[t] = cnt[t];
        __syncthreads();
        for (int o = 1; o < BK; o <<= 1) {
            int v = (t < BK && t >= o) ? sc[t - o] : 0;
            __syncthreads();
            if (t < BK) sc[t] += v;
            __syncthreads();
        }
        if (t < BK) {
            int c = cnt[t];
            off[t] = sc[t] - c;                      // exclusive prefix
            if (n0 + t < N) {
                begend[n0 + t] = make_int2(beg + off[t], beg + sc[t]);
                dinv[n0 + t] = rsqrtf((float)c + 1.0f);
            }
            cnt[t] = 0;                              // becomes fill counter
        }
        __syncthreads();
        for (int i = t; i < ecnt; i += 256) {
            int e = ebuf[beg + i];
            int dl = e >> 20;
            int p = beg + off[dl] + atomicAdd(&cnt[dl], 1);
            col[p] = e & 0xFFFFF;
        }
        return;
    }

    // ---- MFMA GEMM1 tile ----
    const int row0 = ((int)blockIdx.x - NBK) * 64;
    {
        int r = t >> 2, cc = (t & 3) * 32;
        int grow = row0 + r;
        unsigned int* dst = (unsigned int*)&lds[r * 136 + cc];
        if (grow < N) {
            const float4* src = (const float4*)(x + (size_t)grow * 128 + cc);
            #pragma unroll
            for (int i = 0; i < 8; ++i) {
                float4 v = src[i];
                dst[2 * i]     = pack2(v.x, v.y);
                dst[2 * i + 1] = pack2(v.z, v.w);
            }
        } else {
            #pragma unroll
            for (int i = 0; i < 16; ++i) dst[i] = 0;
        }
    }
    __syncthreads();
    const int w = t >> 6, lane = t & 63;
    const int quad = lane >> 4, m = lane & 15;
    short8 a[4];
    #pragma unroll
    for (int ks = 0; ks < 4; ++ks)
        a[ks] = *(const short8*)&lds[(w * 16 + m) * 136 + ks * 32 + quad * 8];
    float4v acc[8];
    #pragma unroll
    for (int nt = 0; nt < 8; ++nt) acc[nt] = (float4v){0.f, 0.f, 0.f, 0.f};
    const short8* wf = (const short8*)w1f;
    #pragma unroll
    for (int nt = 0; nt < 8; ++nt)
        #pragma unroll
        for (int ks = 0; ks < 4; ++ks)
            acc[nt] = __builtin_amdgcn_mfma_f32_16x16x32_bf16(a[ks], wf[(nt * 4 + ks) * 64 + lane],
                                                              acc[nt], 0, 0, 0);
    #pragma unroll
    for (int nt = 0; nt < 8; ++nt)
        #pragma unroll
        for (int r = 0; r < 4; ++r) {
            int grow = row0 + w * 16 + quad * 4 + r;   // C/D: col=lane&15, row=quad*4+reg
            if (grow < N) h[(size_t)grow * 128 + nt * 16 + m] = f2b(acc[nt][r]);
        }
}

// ---------------- agg layer 1 + bias + ReLU + bf16: one node per 16 lanes ----------
// feat rows = 16 uint4 (128 bf16); 16 outstanding row-gathers per wave
__global__ __launch_bounds__(256) void k_agg128e(const uint4* __restrict__ feat,
                                                 const int2* __restrict__ begend,
                                                 const int* __restrict__ col,
                                                 const float* __restrict__ dinv,
                                                 const float* __restrict__ b1,
                                                 uint4* __restrict__ h1b, int N) {
    const int grp = threadIdx.x >> 4;                  // 16 groups per block
    const int l16 = threadIdx.x & 15;
    const int node = blockIdx.x * 16 + grp;
    if (node >= N) return;
    const float dd = dinv[node];
    const int2 be = begend[node];
    const int beg = be.x, end = be.y;
    float a0, a1, a2, a3, a4, a5, a6, a7;
    {
        uint4 sv = feat[(size_t)node * 16 + l16];      // self-loop
        float2 q;
        q = bf2_to_f2(sv.x); a0 = q.x * dd; a1 = q.y * dd;
        q = bf2_to_f2(sv.y); a2 = q.x * dd; a3 = q.y * dd;
        q = bf2_to_f2(sv.z); a4 = q.x * dd; a5 = q.y * dd;
        q = bf2_to_f2(sv.w); a6 = q.x * dd; a7 = q.y * dd;
    }
    int e = beg;
    for (; e + 4 <= end; e += 4) {
        int s0 = col[e], s1 = col[e + 1], s2 = col[e + 2], s3 = col[e + 3];
        float w0 = dinv[s0], w1 = dinv[s1], w2 = dinv[s2], w3 = dinv[s3];
        uint4 u0 = feat[(size_t)s0 * 16 + l16];
        uint4 u1 = feat[(size_t)s1 * 16 + l16];
        uint4 u2 = feat[(size_t)s2 * 16 + l16];
        uint4 u3 = feat[(size_t)s3 * 16 + l16];
        float2 q;
        q = bf2_to_f2(u0.x); a0 += q.x * w0; a1 += q.y * w0;
        q = bf2_to_f2(u0.y); a2 += q.x * w0; a3 += q.y * w0;
        q = bf2_to_f2(u0.z); a4 += q.x * w0; a5 += q.y * w0;
        q = bf2_to_f2(u0.w); a6 += q.x * w0; a7 += q.y * w0;
        q = bf2_to_f2(u1.x); a0 += q.x * w1; a1 += q.y * w1;
        q = bf2_to_f2(u1.y); a2 += q.x * w1; a3 += q.y * w1;
        q = bf2_to_f2(u1.z); a4 += q.x * w1; a5 += q.y * w1;
        q = bf2_to_f2(u1.w); a6 += q.x * w1; a7 += q.y * w1;
        q = bf2_to_f2(u2.x); a0 += q.x * w2; a1 += q.y * w2;
        q = bf2_to_f2(u2.y); a2 += q.x * w2; a3 += q.y * w2;
        q = bf2_to_f2(u2.z); a4 += q.x * w2; a5 += q.y * w2;
        q = bf2_to_f2(u2.w); a6 += q.x * w2; a7 += q.y * w2;
        q = bf2_to_f2(u3.x); a0 += q.x * w3; a1 += q.y * w3;
        q = bf2_to_f2(u3.y); a2 += q.x * w3; a3 += q.y * w3;
        q = bf2_to_f2(u3.z); a4 += q.x * w3; a5 += q.y * w3;
        q = bf2_to_f2(u3.w); a6 += q.x * w3; a7 += q.y * w3;
    }
    for (; e < end; ++e) {
        int s = col[e];
        float w = dinv[s];
        uint4 u = feat[(size_t)s * 16 + l16];
        float2 q;
        q = bf2_to_f2(u.x); a0 += q.x * w; a1 += q.y * w;
        q = bf2_to_f2(u.y); a2 += q.x * w; a3 += q.y * w;
        q = bf2_to_f2(u.z); a4 += q.x * w; a5 += q.y * w;
        q = bf2_to_f2(u.w); a6 += q.x * w; a7 += q.y * w;
    }
    float4 ba = ((const float4*)b1)[2 * l16];
    float4 bb = ((const float4*)b1)[2 * l16 + 1];
    a0 = fmaxf(a0 * dd + ba.x, 0.0f);
    a1 = fmaxf(a1 * dd + ba.y, 0.0f);
    a2 = fmaxf(a2 * dd + ba.z, 0.0f);
    a3 = fmaxf(a3 * dd + ba.w, 0.0f);
    a4 = fmaxf(a4 * dd + bb.x, 0.0f);
    a5 = fmaxf(a5 * dd + bb.y, 0.0f);
    a6 = fmaxf(a6 * dd + bb.z, 0.0f);
    a7 = fmaxf(a7 * dd + bb.w, 0.0f);
    uint4 o;
    o.x = pack2(a0, a1);
    o.y = pack2(a2, a3);
    o.z = pack2(a4, a5);
    o.w = pack2(a6, a7);
    h1b[(size_t)node * 16 + l16] = o;
}

// ---------------- MFMA GEMM2: h2[N,64] = h1b(bf16) @ bf16(W2), bf16 store ----------------
__global__ __launch_bounds__(256) void k_mg2(const unsigned int* __restrict__ h1b,
                                             const unsigned short* __restrict__ w2f,
                                             unsigned short* __restrict__ h2, int N) {
    __shared__ unsigned short lds[64 * 136];
    const int t = threadIdx.x;
    const int row0 = blockIdx.x * 64;
    {   // stage: straight bf16 copy (bias+relu already applied)
        int r = t >> 2, cc = (t & 3) * 32;
        int grow = row0 + r;
        uint4* dst = (uint4*)&lds[r * 136 + cc];
        if (grow < N) {
            const uint4* src = (const uint4*)(h1b + (size_t)grow * 64 + (cc >> 1));
            #pragma unroll
            for (int i = 0; i < 4; ++i) dst[i] = src[i];
        } else {
            #pragma unroll
            for (int i = 0; i < 4; ++i) dst[i] = (uint4){0, 0, 0, 0};
        }
    }
    __syncthreads();
    const int w = t >> 6, lane = t & 63;
    const int quad = lane >> 4, m = lane & 15;
    short8 a[4];
    #pragma unroll
    for (int ks = 0; ks < 4; ++ks)
        a[ks] = *(const short8*)&lds[(w * 16 + m) * 136 + ks * 32 + quad * 8];
    float4v acc[4];
    #pragma unroll
    for (int nt = 0; nt < 4; ++nt) acc[nt] = (float4v){0.f, 0.f, 0.f, 0.f};
    const short8* wf = (const short8*)w2f;
    #pragma unroll
    for (int nt = 0; nt < 4; ++nt)
        #pragma unroll
        for (int ks = 0; ks < 4; ++ks)
            acc[nt] = __builtin_amdgcn_mfma_f32_16x16x32_bf16(a[ks], wf[(nt * 4 + ks) * 64 + lane],
                                                              acc[nt], 0, 0, 0);
    #pragma unroll
    for (int nt = 0; nt < 4; ++nt)
        #pragma unroll
        for (int r = 0; r < 4; ++r) {
            int grow = row0 + w * 16 + quad * 4 + r;
            if (grow < N) h2[(size_t)grow * 64 + nt * 16 + m] = f2b(acc[nt][r]);
        }
}

// ---------------- agg layer 2: one node per 16 lanes, +b2, out fp32 ----------------
__global__ __launch_bounds__(256) void k_agg64(const uint2* __restrict__ feat,
                                               const int2* __restrict__ begend,
                                               const int* __restrict__ col,
                                               const float* __restrict__ dinv,
                                               const float* __restrict__ bias,
                                               float* __restrict__ out, int N) {
    const int grp = threadIdx.x >> 4;
    const int l16 = threadIdx.x & 15;
    const int node = blockIdx.x * 16 + grp;
    if (node >= N) return;
    const float dd = dinv[node];
    const int2 be = begend[node];
    const int beg = be.x, end = be.y;
    float a0, a1, a2, a3;
    {
        uint2 sv = feat[(size_t)node * 16 + l16];      // self-loop
        float2 q;
        q = bf2_to_f2(sv.x); a0 = q.x * dd; a1 = q.y * dd;
        q = bf2_to_f2(sv.y); a2 = q.x * dd; a3 = q.y * dd;
    }
    int e = beg;
    for (; e + 4 <= end; e += 4) {
        int s0 = col[e], s1 = col[e + 1], s2 = col[e + 2], s3 = col[e + 3];
        float w0 = dinv[s0], w1 = dinv[s1], w2 = dinv[s2], w3 = dinv[s3];
        uint2 u0 = feat[(size_t)s0 * 16 + l16];
        uint2 u1 = feat[(size_t)s1 * 16 + l16];
        uint2 u2 = feat[(size_t)s2 * 16 + l16];
        uint2 u3 = feat[(size_t)s3 * 16 + l16];
        float2 q;
        q = bf2_to_f2(u0.x); a0 += q.x * w0; a1 += q.y * w0;
        q = bf2_to_f2(u0.y); a2 += q.x * w0; a3 += q.y * w0;
        q = bf2_to_f2(u1.x); a0 += q.x * w1; a1 += q.y * w1;
        q = bf2_to_f2(u1.y); a2 += q.x * w1; a3 += q.y * w1;
        q = bf2_to_f2(u2.x); a0 += q.x * w2; a1 += q.y * w2;
        q = bf2_to_f2(u2.y); a2 += q.x * w2; a3 += q.y * w2;
        q = bf2_to_f2(u3.x); a0 += q.x * w3; a1 += q.y * w3;
        q = bf2_to_f2(u3.y); a2 += q.x * w3; a3 += q.y * w3;
    }
    for (; e < end; ++e) {
        int s = col[e];
        float w = dinv[s];
        uint2 u = feat[(size_t)s * 16 + l16];
        float2 q;
        q = bf2_to_f2(u.x); a0 += q.x * w; a1 += q.y * w;
        q = bf2_to_f2(u.y); a2 += q.x * w; a3 += q.y * w;
    }
    float4 b = ((const float4*)bias)[l16];
    float4 o;
    o.x = a0 * dd + b.x;
    o.y = a1 * dd + b.y;
    o.z = a2 * dd + b.z;
    o.w = a3 * dd + b.w;
    ((float4*)out)[(size_t)node * 16 + l16] = o;
}

extern "C" void kernel_launch(void* const* d_in, const int* in_sizes, int n_in,
                              void* d_out, int out_size, void* d_ws, size_t ws_size,
                              hipStream_t stream) {
    const float* x  = (const float*)d_in[0];
    const int*   ei = (const int*)d_in[1];
    const float* W1 = (const float*)d_in[2];
    const float* b1 = (const float*)d_in[3];
    const float* W2 = (const float*)d_in[4];
    const float* b2 = (const float*)d_in[5];

    const int N = in_sizes[0] / IN_C;               // 50000
    const int E = in_sizes[1] / 2;                  // 800000
    const int NBK  = (N + BK - 1) / BK;             // 391 buckets
    const int NCHK = (E + 2047) / 2048;             // 391 edge chunks
    const int NT1  = (N + 63) / 64;                 // 782 GEMM tiles

    char* ws = (char*)d_ws;
    int*            flag    = (int*)(ws + 0);
    int*            bfill   = (int*)(ws + 64);
    int2*           begend  = (int2*)(ws + 4096);
    float*          dinv    = (float*)(ws + 404480);
    unsigned short* w1f     = (unsigned short*)(ws + 604672);
    unsigned short* w2f     = (unsigned short*)(ws + 637440);
    int*            ebuf    = (int*)(ws + 655360);               // NBK<<CAPLG packed ints
    int*            col     = (int*)(ws + 7061504);
    unsigned short* h       = (unsigned short*)(ws + 13467904);  // bf16 [N,128]; reused as h2 [N,64]
    uint4*          h1b     = (uint4*)(ws + 26267904);           // bf16 [N,128] packed

    // ---- setup (weights + dtype probe + bfill zero) ----
    k_setup<<<96, 256, 0, stream>>>(W1, W2, ei, w1f, w2f, flag, bfill, NBK);

    // ---- single-pass bucket partition (fixed-capacity regions) ----
    k_bpart<<<NCHK, 256, 0, stream>>>(ei, flag, bfill, ebuf, E, NBK);

    // ---- fused: bucket-local CSR finalize + GEMM1 ----
    k_blmg1<<<NBK + NT1, 256, 0, stream>>>(ebuf, bfill, begend, dinv, col,
                                           x, w1f, h, N, NBK);

    // ---- layer 1 aggregation (+b1, ReLU, bf16) ----
    k_agg128e<<<(N + 15) / 16, 256, 0, stream>>>((const uint4*)h, begend, col, dinv, b1, h1b, N);

    // ---- layer 2 ----
    unsigned short* h2 = h;                          // h dead after agg128e
    k_mg2<<<NT1, 256, 0, stream>>>((const unsigned int*)h1b, w2f, h2, N);
    k_agg64<<<(N + 15) / 16, 256, 0, stream>>>((const uint2*)h2, begend, col, dinv, b2, (float*)d_out, N);
}